// Round 1
// baseline (794.857 us; speedup 1.0000x reference)
//
#include <hip/hip_runtime.h>

typedef unsigned short u16;
typedef unsigned int u32;

__device__ __forceinline__ float b2f(u16 h) {
  union { u32 u; float f; } v; v.u = ((u32)h) << 16; return v.f;
}
__device__ __forceinline__ u16 f2b(float x) {
  union { float f; u32 u; } v; v.f = x;
  u32 u = v.u;
  return (u16)((u + 0x7FFFu + ((u >> 16) & 1u)) >> 16);  // RTN-even
}
__device__ __forceinline__ void up2(u32 u, float& lo, float& hi) {
  union { u32 x; float f; } a, b;
  a.x = u << 16; b.x = u & 0xFFFF0000u;
  lo = a.f; hi = b.f;
}
__device__ __forceinline__ u32 pk2(float lo, float hi) {
  return (u32)f2b(lo) | ((u32)f2b(hi) << 16);
}

// ---------------- prep: weight transposes / folds (bf16) ----------------
// modwT [c][640]        = mod_w[k][c]
// c1wT  [k][64]         = conv1_w[o][k] * m_items[k]     (m_items folded HERE only)
// c2T   [c][64]         = conv2_w[o][c]
// wpreT [c][128]        = wf_pre_w[o][c]
// wtconv[(ic*9+dy*3+dx)][128] = wf_post_w[o][ic][dy][dx] * bn_scale(o)
// pewT  [k=2048][128]   = pe_w[o][k]
__global__ __launch_bounds__(256) void k_prep(
    const float* __restrict__ mod_w, const float* __restrict__ conv1_w,
    const float* __restrict__ m_items, const float* __restrict__ conv2_w,
    const float* __restrict__ wf_pre_w, const float* __restrict__ wf_post_w,
    const float* __restrict__ wf_bn_g, const float* __restrict__ pe_w,
    u16* __restrict__ modwT, u16* __restrict__ c1wT, u16* __restrict__ c2T,
    u16* __restrict__ wpreT, u16* __restrict__ wtconv, u16* __restrict__ pewT)
{
  int idx = blockIdx.x * 256 + threadIdx.x;
  if (idx < 81920) {
    int c = idx / 640, k = idx % 640;
    modwT[idx] = f2b(mod_w[k * 128 + c]);
  } else if (idx < 122880) {
    int i = idx - 81920; int k = i >> 6, o = i & 63;
    c1wT[i] = f2b(conv1_w[o * 640 + k] * m_items[k]);
  } else if (idx < 131072) {
    int i = idx - 122880; int c = i >> 6, o = i & 63;
    c2T[i] = f2b(conv2_w[o * 128 + c]);
  } else if (idx < 147456) {
    int i = idx - 131072; int c = i >> 7, o = i & 127;
    wpreT[i] = f2b(wf_pre_w[o * 128 + c]);
  } else if (idx < 294912) {
    int i = idx - 147456; int row = i >> 7, o = i & 127;
    int ic = row / 9, rr = row % 9, dy = rr / 3, dx = rr % 3;
    float scale = wf_bn_g[o] * rsqrtf(1.f + 1e-5f);
    wtconv[i] = f2b(wf_post_w[((o * 128 + ic) * 3 + dy) * 3 + dx] * scale);
  } else if (idx < 557056) {
    int i = idx - 294912; int k = i >> 7, o = i & 127;
    pewT[i] = f2b(pe_w[o * 2048 + k]);
  }
}

// ---------------- kernel A: fused read() -> Sn [B,128,H,W] ----------------
// Per block: 128 pixels. l2norm folded via rn; mod GEMM (K=128) chunked over
// k (64 at a time) -> sigmoid -> modbuf(LDS) -> GEMM2 accumulates M0c (o=64).
// Then Sc = conv2 GEMM. Sn = concat(M0c+b1, Sc+b2).
__global__ __launch_bounds__(256) void k_read(
    const float* __restrict__ S, const u16* __restrict__ modwT,
    const u16* __restrict__ c1wT, const u16* __restrict__ c2T,
    const float* __restrict__ mod_b,
    const float* __restrict__ conv1_b, const float* __restrict__ conv2_b,
    float* __restrict__ Sn)
{
  __shared__ u16 xs[128][136];     // [c][pix], unnormalized x, bf16
  __shared__ u16 wch[128][68];     // [c][kk] mod_w chunk (reused for c2T)
  __shared__ u16 modbuf[64][136];  // [kk][pix] sigmoid output
  __shared__ u16 c1l[64][68];      // [kk][o]
  __shared__ float rn[128];
  __shared__ float ps[2][128];

  const int t = threadIdx.x;
  const int bx = blockIdx.x;
  const int b = bx >> 7;
  const int hw0 = (bx & 127) << 7;

  { // stage x, compute sumsq
    const int pix = t & 127, ch = t >> 7;
    const float* Sp = S + ((size_t)b << 21) + (size_t)hw0 + pix;
    float ss = 0.f;
    #pragma unroll 8
    for (int cc = 0; cc < 64; ++cc) {
      int c = (cc << 1) + ch;
      float v = Sp[(size_t)c << 14];
      ss += v * v;
      xs[c][pix] = f2b(v);
    }
    ps[ch][pix] = ss;
  }
  __syncthreads();
  if (t < 128) {
    float ss = ps[0][t] + ps[1][t];
    rn[t] = 1.f / fmaxf(sqrtf(ss), 1e-12f);
  }
  __syncthreads();

  const int tk = t >> 4, tp = t & 15;   // micro-tile: 4 k/o x 8 pix
  float rnv[8];
  #pragma unroll
  for (int j = 0; j < 8; ++j) rnv[j] = rn[(tp << 3) + j];

  float acc2[4][8];
  #pragma unroll
  for (int i = 0; i < 4; ++i)
    #pragma unroll
    for (int j = 0; j < 8; ++j) acc2[i][j] = 0.f;

  for (int k0 = 0; k0 < 640; k0 += 64) {
    __syncthreads();
    #pragma unroll
    for (int r = 0; r < 32; ++r) {       // stage mod_w chunk [c][kk]
      int idx = (r << 8) + t;
      int c = idx >> 6, kk = idx & 63;
      wch[c][kk] = modwT[c * 640 + k0 + kk];
    }
    #pragma unroll
    for (int r = 0; r < 16; ++r) {       // stage c1wT chunk [kk][o]
      int idx = (r << 8) + t;
      int kk = idx >> 6, o = idx & 63;
      c1l[kk][o] = c1wT[((k0 + kk) << 6) + o];
    }
    __syncthreads();

    float acc1[4][8];
    #pragma unroll
    for (int i = 0; i < 4; ++i)
      #pragma unroll
      for (int j = 0; j < 8; ++j) acc1[i][j] = 0.f;

    #pragma unroll 2
    for (int c = 0; c < 128; ++c) {
      float xv[8], wv[4];
      uint4 xu = *(const uint4*)&xs[c][tp << 3];
      up2(xu.x, xv[0], xv[1]); up2(xu.y, xv[2], xv[3]);
      up2(xu.z, xv[4], xv[5]); up2(xu.w, xv[6], xv[7]);
      uint2 wu = *(const uint2*)&wch[c][tk << 2];
      up2(wu.x, wv[0], wv[1]); up2(wu.y, wv[2], wv[3]);
      #pragma unroll
      for (int i = 0; i < 4; ++i)
        #pragma unroll
        for (int j = 0; j < 8; ++j)
          acc1[i][j] = fmaf(wv[i], xv[j], acc1[i][j]);
    }

    float4 mb = *(const float4*)&mod_b[k0 + (tk << 2)];
    #pragma unroll
    for (int i = 0; i < 4; ++i) {
      float mbv = ((const float*)&mb)[i];
      float m[8];
      #pragma unroll
      for (int j = 0; j < 8; ++j) {
        float z = acc1[i][j] * rnv[j] + mbv;
        m[j] = 1.f / (1.f + __expf(-z));
      }
      uint4 st;
      st.x = pk2(m[0], m[1]); st.y = pk2(m[2], m[3]);
      st.z = pk2(m[4], m[5]); st.w = pk2(m[6], m[7]);
      *(uint4*)&modbuf[(tk << 2) + i][tp << 3] = st;
    }
    __syncthreads();

    #pragma unroll 2
    for (int kk = 0; kk < 64; ++kk) {
      float mv[8], cv[4];
      uint4 mu = *(const uint4*)&modbuf[kk][tp << 3];
      up2(mu.x, mv[0], mv[1]); up2(mu.y, mv[2], mv[3]);
      up2(mu.z, mv[4], mv[5]); up2(mu.w, mv[6], mv[7]);
      uint2 cu = *(const uint2*)&c1l[kk][tk << 2];
      up2(cu.x, cv[0], cv[1]); up2(cu.y, cv[2], cv[3]);
      #pragma unroll
      for (int i = 0; i < 4; ++i)
        #pragma unroll
        for (int j = 0; j < 8; ++j)
          acc2[i][j] = fmaf(cv[i], mv[j], acc2[i][j]);
    }
  }

  __syncthreads();
  #pragma unroll
  for (int r = 0; r < 32; ++r) {   // stage c2T into wch
    int idx = (r << 8) + t;
    int c = idx >> 6, o = idx & 63;
    wch[c][o] = c2T[(c << 6) + o];
  }
  __syncthreads();

  float acc3[4][8];
  #pragma unroll
  for (int i = 0; i < 4; ++i)
    #pragma unroll
    for (int j = 0; j < 8; ++j) acc3[i][j] = 0.f;

  #pragma unroll 2
  for (int c = 0; c < 128; ++c) {
    float xv[8], wv[4];
    uint4 xu = *(const uint4*)&xs[c][tp << 3];
    up2(xu.x, xv[0], xv[1]); up2(xu.y, xv[2], xv[3]);
    up2(xu.z, xv[4], xv[5]); up2(xu.w, xv[6], xv[7]);
    uint2 wu = *(const uint2*)&wch[c][tk << 2];
    up2(wu.x, wv[0], wv[1]); up2(wu.y, wv[2], wv[3]);
    #pragma unroll
    for (int i = 0; i < 4; ++i)
      #pragma unroll
      for (int j = 0; j < 8; ++j)
        acc3[i][j] = fmaf(wv[i], xv[j], acc3[i][j]);
  }

  float4 c1b = *(const float4*)&conv1_b[tk << 2];
  float4 c2b = *(const float4*)&conv2_b[tk << 2];
  size_t base = ((size_t)b << 21) + (size_t)hw0 + (tp << 3);
  #pragma unroll
  for (int i = 0; i < 4; ++i) {
    int o = (tk << 2) + i;
    float ob = ((const float*)&c1b)[i];
    float* p0 = Sn + base + ((size_t)o << 14);
    float4 v0 = { acc2[i][0] + ob, acc2[i][1] + ob, acc2[i][2] + ob, acc2[i][3] + ob };
    float4 v1 = { acc2[i][4] + ob, acc2[i][5] + ob, acc2[i][6] + ob, acc2[i][7] + ob };
    *(float4*)p0 = v0; *(float4*)(p0 + 4) = v1;
    float sb = ((const float*)&c2b)[i];
    float* p1 = Sn + base + ((size_t)(o + 64) << 14);
    float4 u0 = { rnv[0]*acc3[i][0] + sb, rnv[1]*acc3[i][1] + sb,
                  rnv[2]*acc3[i][2] + sb, rnv[3]*acc3[i][3] + sb };
    float4 u1 = { rnv[4]*acc3[i][4] + sb, rnv[5]*acc3[i][5] + sb,
                  rnv[6]*acc3[i][6] + sb, rnv[7]*acc3[i][7] + sb };
    *(float4*)p1 = u0; *(float4*)(p1 + 4) = u1;
  }
}

// ---------------- kernel B: PatchEmbed (4x4/s4 conv + LN) -> f [4096][128] ----
// Block = 8 consecutive patches (one ph row segment), 128 threads (thread=o).
__global__ __launch_bounds__(128) void k_pembed(
    const float* __restrict__ Sn, const u16* __restrict__ pewT,
    const float* __restrict__ pe_b, const float* __restrict__ pe_g,
    const float* __restrict__ pe_beta, float* __restrict__ f)
{
  __shared__ float pat[8][2048];
  __shared__ float fln[8][128];
  __shared__ float pm[8][16], pv[8][16], ms[8], rs[8];
  const int t = threadIdx.x, bx = blockIdx.x;
  const int b = bx >> 7, rem = bx & 127;
  const int ph = rem >> 2, pw0 = (rem & 3) << 3;

  for (int r = 0; r < 128; ++r) {   // 16384 elems
    int e = (r << 7) + t;
    int row = e >> 5, q32 = e & 31;
    int c = row >> 2, p = row & 3;
    float v = Sn[((size_t)((b * 128 + c) * 128 + (ph * 4 + p))) * 128 + pw0 * 4 + q32];
    pat[q32 >> 2][c * 16 + p * 4 + (q32 & 3)] = v;
  }
  __syncthreads();

  float acc[8];
  #pragma unroll
  for (int j = 0; j < 8; ++j) acc[j] = 0.f;
  for (int idx = 0; idx < 2048; idx += 4) {
    float w0 = b2f(pewT[(size_t)(idx + 0) * 128 + t]);
    float w1 = b2f(pewT[(size_t)(idx + 1) * 128 + t]);
    float w2 = b2f(pewT[(size_t)(idx + 2) * 128 + t]);
    float w3 = b2f(pewT[(size_t)(idx + 3) * 128 + t]);
    #pragma unroll
    for (int j = 0; j < 8; ++j) {
      float4 p4 = *(const float4*)&pat[j][idx];
      acc[j] = fmaf(p4.x, w0, acc[j]);
      acc[j] = fmaf(p4.y, w1, acc[j]);
      acc[j] = fmaf(p4.z, w2, acc[j]);
      acc[j] = fmaf(p4.w, w3, acc[j]);
    }
  }
  float pb = pe_b[t];
  #pragma unroll
  for (int j = 0; j < 8; ++j) fln[j][t] = acc[j] + pb;
  __syncthreads();
  {
    int j = t >> 4, l = t & 15;
    float s1 = 0.f, s2 = 0.f;
    #pragma unroll
    for (int i = 0; i < 8; ++i) { float v = fln[j][l * 8 + i]; s1 += v; s2 += v * v; }
    pm[j][l] = s1; pv[j][l] = s2;
  }
  __syncthreads();
  if (t < 8) {
    float s1 = 0.f, s2 = 0.f;
    #pragma unroll
    for (int i = 0; i < 16; ++i) { s1 += pm[t][i]; s2 += pv[t][i]; }
    float m = s1 * (1.f / 128.f);
    float var = s2 * (1.f / 128.f) - m * m;
    ms[t] = m; rs[t] = rsqrtf(var + 1e-5f);
  }
  __syncthreads();
  int pbase = (b * 32 + ph) * 32 + pw0;
  float g = pe_g[t], be = pe_beta[t];
  #pragma unroll
  for (int j = 0; j < 8; ++j) {
    float v = (fln[j][t] - ms[j]) * rs[j] * g + be;
    f[(size_t)(pbase + j) * 128 + t] = v;
  }
}

// ---------------- kernel C: PatchExpand + LN(32) + up-proj -> M1 NHWC -------
// Block = 4 patch positions, 128 threads.
__global__ __launch_bounds__(128) void k_expand(
    const float* __restrict__ f, const float* __restrict__ exp_w,
    const float* __restrict__ fin_g, const float* __restrict__ fin_b,
    const float* __restrict__ up_w, const float* __restrict__ up_b,
    float* __restrict__ M1)
{
  __shared__ float fr[4][128];
  __shared__ float fe[4][512];
  __shared__ float sm[64], sr[64];
  const int t = threadIdx.x, bx = blockIdx.x;
  const int b = bx >> 8, rem = bx & 255;
  const int ph = rem >> 3, pw0 = (rem & 7) << 2;
  const int pbase = (b * 32 + ph) * 32 + pw0;

  #pragma unroll
  for (int j = 0; j < 4; ++j) fr[j][t] = f[(size_t)(pbase + j) * 128 + t];
  __syncthreads();

  float acc[4][4]; // [col-block][patch]
  #pragma unroll
  for (int i = 0; i < 4; ++i)
    #pragma unroll
    for (int j = 0; j < 4; ++j) acc[i][j] = 0.f;
  for (int c = 0; c < 128; ++c) {
    float f0 = fr[0][c], f1 = fr[1][c], f2 = fr[2][c], f3 = fr[3][c];
    #pragma unroll
    for (int i = 0; i < 4; ++i) {
      float w = exp_w[(size_t)c * 512 + (i << 7) + t];
      acc[i][0] = fmaf(f0, w, acc[i][0]);
      acc[i][1] = fmaf(f1, w, acc[i][1]);
      acc[i][2] = fmaf(f2, w, acc[i][2]);
      acc[i][3] = fmaf(f3, w, acc[i][3]);
    }
  }
  #pragma unroll
  for (int i = 0; i < 4; ++i)
    #pragma unroll
    for (int pp = 0; pp < 4; ++pp) fe[pp][(i << 7) + t] = acc[i][pp];
  __syncthreads();

  if (t < 64) {
    int pp = t >> 4, sp = t & 15;
    float s1 = 0.f, s2 = 0.f;
    for (int i = 0; i < 32; ++i) {
      float v = fe[pp][sp * 32 + ((t + i) & 31)];
      s1 += v; s2 += v * v;
    }
    float m = s1 * (1.f / 32.f);
    float var = s2 * (1.f / 32.f) - m * m;
    sm[t] = m; sr[t] = rsqrtf(var + 1e-5f);
  }
  __syncthreads();
  #pragma unroll
  for (int r = 0; r < 16; ++r) {
    int idx = (r << 7) + t;
    int pp = idx >> 9, j = idx & 511;
    int gi = idx >> 5, cc = idx & 31;
    float v = fe[pp][j];
    fe[pp][j] = (v - sm[gi]) * sr[gi] * fin_g[cc] + fin_b[cc];
  }
  __syncthreads();

  float uw[32];
  #pragma unroll
  for (int i = 0; i < 32; i += 4) {
    float4 u4 = *(const float4*)&up_w[t * 32 + i];
    uw[i] = u4.x; uw[i + 1] = u4.y; uw[i + 2] = u4.z; uw[i + 3] = u4.w;
  }
  float ub = up_b[t];
  for (int pp = 0; pp < 4; ++pp) {
    for (int sp = 0; sp < 16; ++sp) {
      int p = sp >> 2, q = sp & 3;
      float s = ub;
      #pragma unroll
      for (int cc = 0; cc < 32; ++cc) s = fmaf(fe[pp][sp * 32 + cc], uw[cc], s);
      M1[(((size_t)(b * 128 + ph * 4 + p)) * 128 + ((pw0 + pp) * 4 + q)) * 128 + t] = s;
    }
  }
}

// ---------------- kernel D: x = fwt0*(query@WpreT) + fwt1*M1 (NCHW out) -----
__global__ __launch_bounds__(256) void k_wf(
    const float* __restrict__ Q, const u16* __restrict__ wpreT,
    const float* __restrict__ M1, const float* __restrict__ w2,
    float* __restrict__ X)
{
  __shared__ u16 qs[128][136];
  __shared__ u16 wl[128][136];
  const int t = threadIdx.x, bx = blockIdx.x;
  const int b = bx >> 7;
  const int hw0 = (bx & 127) << 7;
  {
    const int pix = t & 127, ch = t >> 7;
    const float* Qp = Q + ((size_t)b << 21) + (size_t)hw0 + pix;
    #pragma unroll 8
    for (int cc = 0; cc < 64; ++cc) {
      int c = (cc << 1) + ch;
      qs[c][pix] = f2b(Qp[(size_t)c << 14]);
    }
    #pragma unroll
    for (int r = 0; r < 64; ++r) {
      int idx = (r << 8) + t;
      int c = idx >> 7, o = idx & 127;
      wl[c][o] = wpreT[(c << 7) + o];
    }
  }
  __syncthreads();
  const int to = t >> 4, tp = t & 15;   // 8 o x 8 pix micro
  float acc[8][8];
  #pragma unroll
  for (int i = 0; i < 8; ++i)
    #pragma unroll
    for (int j = 0; j < 8; ++j) acc[i][j] = 0.f;

  #pragma unroll 2
  for (int c = 0; c < 128; ++c) {
    float wv[8], qv[8];
    uint4 wu = *(const uint4*)&wl[c][to << 3];
    up2(wu.x, wv[0], wv[1]); up2(wu.y, wv[2], wv[3]);
    up2(wu.z, wv[4], wv[5]); up2(wu.w, wv[6], wv[7]);
    uint4 qu = *(const uint4*)&qs[c][tp << 3];
    up2(qu.x, qv[0], qv[1]); up2(qu.y, qv[2], qv[3]);
    up2(qu.z, qv[4], qv[5]); up2(qu.w, qv[6], qv[7]);
    #pragma unroll
    for (int i = 0; i < 8; ++i)
      #pragma unroll
      for (int j = 0; j < 8; ++j)
        acc[i][j] = fmaf(wv[i], qv[j], acc[i][j]);
  }
  float a0 = fmaxf(w2[0], 0.f), a1 = fmaxf(w2[1], 0.f);
  float inv = 1.f / (a0 + a1 + 1e-8f);
  float f0 = a0 * inv, f1 = a1 * inv;
  const int o0 = to << 3, p0 = tp << 3;
  float m1r[8][8];
  #pragma unroll
  for (int j = 0; j < 8; ++j) {
    const float* mp = M1 + (((size_t)(b << 14) + hw0 + p0 + j) << 7) + o0;
    float4 u = *(const float4*)mp, v = *(const float4*)(mp + 4);
    m1r[j][0] = u.x; m1r[j][1] = u.y; m1r[j][2] = u.z; m1r[j][3] = u.w;
    m1r[j][4] = v.x; m1r[j][5] = v.y; m1r[j][6] = v.z; m1r[j][7] = v.w;
  }
  #pragma unroll
  for (int i = 0; i < 8; ++i) {
    float* px = X + ((size_t)((b << 7) + o0 + i) << 14) + hw0 + p0;
    float4 v0 = { f0 * acc[i][0] + f1 * m1r[0][i], f0 * acc[i][1] + f1 * m1r[1][i],
                  f0 * acc[i][2] + f1 * m1r[2][i], f0 * acc[i][3] + f1 * m1r[3][i] };
    float4 v1 = { f0 * acc[i][4] + f1 * m1r[4][i], f0 * acc[i][5] + f1 * m1r[5][i],
                  f0 * acc[i][6] + f1 * m1r[6][i], f0 * acc[i][7] + f1 * m1r[7][i] };
    *(float4*)px = v0; *(float4*)(px + 4) = v1;
  }
}

// ---------------- kernel E: 3x3 conv + BN + ReLU6 -> out --------------------
// Block = 8x8 output tile, 256 threads; thread = (to, 4-pixel quad).
__global__ __launch_bounds__(256) void k_conv3(
    const float* __restrict__ X, const u16* __restrict__ wt,
    const float* __restrict__ bnb, float* __restrict__ out)
{
  __shared__ float it[32][10][12];
  __shared__ u16 wl[288][68];
  const int t = threadIdx.x, bx = blockIdx.x;
  const int b = bx >> 8, rem = bx & 255;
  const int py0 = (rem >> 4) << 3, px0 = (rem & 15) << 3;
  const int tp = t & 15, to = t >> 4;
  const int r = tp >> 1, xq = (tp & 1) << 2;

  for (int ot = 0; ot < 2; ++ot) {
    float acc[4][4];
    #pragma unroll
    for (int i = 0; i < 4; ++i)
      #pragma unroll
      for (int j = 0; j < 4; ++j) acc[i][j] = 0.f;

    for (int ic0 = 0; ic0 < 128; ic0 += 32) {
      __syncthreads();
      for (int idx = t; idx < 3200; idx += 256) {
        int ic = idx / 100, remm = idx % 100;
        int ry = remm / 10, cx = remm % 10;
        int gy = py0 + ry - 1, gx = px0 + cx - 1;
        float v = 0.f;
        if (gy >= 0 && gy < 128 && gx >= 0 && gx < 128)
          v = X[((size_t)(b * 128 + ic0 + ic) << 14) + (gy << 7) + gx];
        it[ic][ry][cx] = v;
      }
      #pragma unroll
      for (int rr = 0; rr < 72; ++rr) {
        int idx = (rr << 8) + t;
        int row = idx >> 6, o = idx & 63;
        wl[row][o] = wt[(size_t)(ic0 * 9 + row) * 128 + (ot << 6) + o];
      }
      __syncthreads();

      for (int ic = 0; ic < 32; ++ic) {
        #pragma unroll
        for (int dy = 0; dy < 3; ++dy) {
          #pragma unroll
          for (int dx = 0; dx < 3; ++dx) {
            float v0 = it[ic][r + dy][xq + dx];
            float v1 = it[ic][r + dy][xq + dx + 1];
            float v2 = it[ic][r + dy][xq + dx + 2];
            float v3 = it[ic][r + dy][xq + dx + 3];
            uint2 wu = *(const uint2*)&wl[ic * 9 + dy * 3 + dx][to << 2];
            float w0, w1, w2, w3;
            up2(wu.x, w0, w1); up2(wu.y, w2, w3);
            acc[0][0] = fmaf(w0, v0, acc[0][0]); acc[0][1] = fmaf(w0, v1, acc[0][1]);
            acc[0][2] = fmaf(w0, v2, acc[0][2]); acc[0][3] = fmaf(w0, v3, acc[0][3]);
            acc[1][0] = fmaf(w1, v0, acc[1][0]); acc[1][1] = fmaf(w1, v1, acc[1][1]);
            acc[1][2] = fmaf(w1, v2, acc[1][2]); acc[1][3] = fmaf(w1, v3, acc[1][3]);
            acc[2][0] = fmaf(w2, v0, acc[2][0]); acc[2][1] = fmaf(w2, v1, acc[2][1]);
            acc[2][2] = fmaf(w2, v2, acc[2][2]); acc[2][3] = fmaf(w2, v3, acc[2][3]);
            acc[3][0] = fmaf(w3, v0, acc[3][0]); acc[3][1] = fmaf(w3, v1, acc[3][1]);
            acc[3][2] = fmaf(w3, v2, acc[3][2]); acc[3][3] = fmaf(w3, v3, acc[3][3]);
          }
        }
      }
    }
    #pragma unroll
    for (int i = 0; i < 4; ++i) {
      int o = (ot << 6) + (to << 2) + i;
      float bb = bnb[o];
      float4 v = { fminf(fmaxf(acc[i][0] + bb, 0.f), 6.f),
                   fminf(fmaxf(acc[i][1] + bb, 0.f), 6.f),
                   fminf(fmaxf(acc[i][2] + bb, 0.f), 6.f),
                   fminf(fmaxf(acc[i][3] + bb, 0.f), 6.f) };
      *(float4*)&out[((size_t)(b * 128 + o) << 14) + ((py0 + r) << 7) + px0 + xq] = v;
    }
  }
}

extern "C" void kernel_launch(void* const* d_in, const int* in_sizes, int n_in,
                              void* d_out, int out_size, void* d_ws, size_t ws_size,
                              hipStream_t stream) {
  const float* Structure = (const float*)d_in[0];
  const float* query     = (const float*)d_in[1];
  const float* m_items   = (const float*)d_in[2];
  const float* mod_w     = (const float*)d_in[3];
  const float* mod_b     = (const float*)d_in[4];
  const float* conv1_w   = (const float*)d_in[5];
  const float* conv1_b   = (const float*)d_in[6];
  const float* conv2_w   = (const float*)d_in[7];
  const float* conv2_b   = (const float*)d_in[8];
  const float* pe_w      = (const float*)d_in[9];
  const float* pe_b      = (const float*)d_in[10];
  const float* pe_g      = (const float*)d_in[11];
  const float* pe_beta   = (const float*)d_in[12];
  const float* exp_w     = (const float*)d_in[13];
  const float* fin_g     = (const float*)d_in[14];
  const float* fin_b     = (const float*)d_in[15];
  const float* up_w      = (const float*)d_in[16];
  const float* up_b      = (const float*)d_in[17];
  const float* wf_w2     = (const float*)d_in[18];
  const float* wf_pre_w  = (const float*)d_in[19];
  const float* wf_post_w = (const float*)d_in[20];
  const float* wf_bn_g   = (const float*)d_in[21];
  const float* wf_bn_b   = (const float*)d_in[22];

  char* ws = (char*)d_ws;
  float* Sn = (float*)(ws + 0);              // 33,554,432 B
  float* f  = (float*)(ws + 33554432);       //  2,097,152 B
  float* M1 = (float*)(ws + 35651584);       // 33,554,432 B (NHWC)
  float* X  = (float*)(ws + 0);              // alias Sn (dead after k_pembed)
  u16* modwT  = (u16*)(ws + 69206016);
  u16* c1wT   = (u16*)(ws + 69369856);
  u16* c2T    = (u16*)(ws + 69451776);
  u16* wpreT  = (u16*)(ws + 69468160);
  u16* wtconv = (u16*)(ws + 69500928);
  u16* pewT   = (u16*)(ws + 69795840);       // end at 70,320,128 B

  k_prep<<<2176, 256, 0, stream>>>(mod_w, conv1_w, m_items, conv2_w, wf_pre_w,
                                   wf_post_w, wf_bn_g, pe_w,
                                   modwT, c1wT, c2T, wpreT, wtconv, pewT);
  k_read<<<512, 256, 0, stream>>>(Structure, modwT, c1wT, c2T, mod_b,
                                  conv1_b, conv2_b, Sn);
  k_pembed<<<512, 128, 0, stream>>>(Sn, pewT, pe_b, pe_g, pe_beta, f);
  k_expand<<<1024, 128, 0, stream>>>(f, exp_w, fin_g, fin_b, up_w, up_b, M1);
  k_wf<<<512, 256, 0, stream>>>(query, wpreT, M1, wf_w2, X);
  k_conv3<<<1024, 256, 0, stream>>>(X, wtconv, wf_bn_b, (float*)d_out);
}

// Round 2
// 493.334 us; speedup vs baseline: 1.6112x; 1.6112x over previous
//
#include <hip/hip_runtime.h>

typedef unsigned short u16;
typedef unsigned int u32;
typedef __attribute__((ext_vector_type(8))) short bf16x8;
typedef __attribute__((ext_vector_type(4))) float f32x4;

__device__ __forceinline__ float b2f(u16 h) {
  union { u32 u; float f; } v; v.u = ((u32)h) << 16; return v.f;
}
__device__ __forceinline__ u16 f2b(float x) {
  union { float f; u32 u; } v; v.f = x;
  u32 u = v.u;
  return (u16)((u + 0x7FFFu + ((u >> 16) & 1u)) >> 16);  // RTN-even
}
__device__ __forceinline__ void up2(u32 u, float& lo, float& hi) {
  union { u32 x; float f; } a, b;
  a.x = u << 16; b.x = u & 0xFFFF0000u;
  lo = a.f; hi = b.f;
}
__device__ __forceinline__ u32 pk2(float lo, float hi) {
  return (u32)f2b(lo) | ((u32)f2b(hi) << 16);
}

// ---------------- prep: weight transposes / folds (bf16) ----------------
// modwT [c][640]        = mod_w[k][c]
// c1wT  [k][64]         = conv1_w[o][k] * m_items[k]
// c2T   [c][64]         = conv2_w[o][c]
// wpreT [c][128]        = wf_pre_w[o][c]
// wpk: conv3 weights in MFMA B-fragment order:
//   wpk[(((ks*9+tap)*8+n)*64+lane)*8+i] = w[o=n*16+(lane&15)][ic=ks*32+(lane>>4)*8+i][tap] * bnscale(o)
// pewT  [k=2048][128]   = pe_w[o][k]
__global__ __launch_bounds__(256) void k_prep(
    const float* __restrict__ mod_w, const float* __restrict__ conv1_w,
    const float* __restrict__ m_items, const float* __restrict__ conv2_w,
    const float* __restrict__ wf_pre_w, const float* __restrict__ wf_post_w,
    const float* __restrict__ wf_bn_g, const float* __restrict__ pe_w,
    u16* __restrict__ modwT, u16* __restrict__ c1wT, u16* __restrict__ c2T,
    u16* __restrict__ wpreT, u16* __restrict__ wpk, u16* __restrict__ pewT)
{
  int idx = blockIdx.x * 256 + threadIdx.x;
  if (idx < 81920) {
    int c = idx / 640, k = idx % 640;
    modwT[idx] = f2b(mod_w[k * 128 + c]);
  } else if (idx < 122880) {
    int i = idx - 81920; int k = i >> 6, o = i & 63;
    c1wT[i] = f2b(conv1_w[o * 640 + k] * m_items[k]);
  } else if (idx < 131072) {
    int i = idx - 122880; int c = i >> 6, o = i & 63;
    c2T[i] = f2b(conv2_w[o * 128 + c]);
  } else if (idx < 147456) {
    int i = idx - 131072; int c = i >> 7, o = i & 127;
    wpreT[i] = f2b(wf_pre_w[o * 128 + c]);
  } else if (idx < 294912) {
    int i2 = idx - 147456;           // 0..147455
    int e = i2 & 7;
    int r = i2 >> 3;
    int lane = r & 63; r >>= 6;
    int n = r & 7; r >>= 3;          // r = ks*9+tap, 0..35
    int tap = r % 9, ks = r / 9;
    int o = (n << 4) + (lane & 15);
    int ic = (ks << 5) + ((lane >> 4) << 3) + e;
    int dy = tap / 3, dx = tap % 3;
    float scale = wf_bn_g[o] * rsqrtf(1.f + 1e-5f);
    wpk[i2] = f2b(wf_post_w[((o * 128 + ic) * 3 + dy) * 3 + dx] * scale);
  } else if (idx < 557056) {
    int i = idx - 294912; int k = i >> 7, o = i & 127;
    pewT[i] = f2b(pe_w[o * 2048 + k]);
  }
}

// ---------------- kernel A: fused read() -> Sn [B,128,H,W] ----------------
__global__ __launch_bounds__(256) void k_read(
    const float* __restrict__ S, const u16* __restrict__ modwT,
    const u16* __restrict__ c1wT, const u16* __restrict__ c2T,
    const float* __restrict__ mod_b,
    const float* __restrict__ conv1_b, const float* __restrict__ conv2_b,
    float* __restrict__ Sn)
{
  __shared__ u16 xs[128][136];
  __shared__ u16 wch[128][68];
  __shared__ u16 modbuf[64][136];
  __shared__ u16 c1l[64][68];
  __shared__ float rn[128];
  __shared__ float ps[2][128];

  const int t = threadIdx.x;
  const int bx = blockIdx.x;
  const int b = bx >> 7;
  const int hw0 = (bx & 127) << 7;

  {
    const int pix = t & 127, ch = t >> 7;
    const float* Sp = S + ((size_t)b << 21) + (size_t)hw0 + pix;
    float ss = 0.f;
    #pragma unroll 8
    for (int cc = 0; cc < 64; ++cc) {
      int c = (cc << 1) + ch;
      float v = Sp[(size_t)c << 14];
      ss += v * v;
      xs[c][pix] = f2b(v);
    }
    ps[ch][pix] = ss;
  }
  __syncthreads();
  if (t < 128) {
    float ss = ps[0][t] + ps[1][t];
    rn[t] = 1.f / fmaxf(sqrtf(ss), 1e-12f);
  }
  __syncthreads();

  const int tk = t >> 4, tp = t & 15;
  float rnv[8];
  #pragma unroll
  for (int j = 0; j < 8; ++j) rnv[j] = rn[(tp << 3) + j];

  float acc2[4][8];
  #pragma unroll
  for (int i = 0; i < 4; ++i)
    #pragma unroll
    for (int j = 0; j < 8; ++j) acc2[i][j] = 0.f;

  for (int k0 = 0; k0 < 640; k0 += 64) {
    __syncthreads();
    #pragma unroll
    for (int r = 0; r < 32; ++r) {
      int idx = (r << 8) + t;
      int c = idx >> 6, kk = idx & 63;
      wch[c][kk] = modwT[c * 640 + k0 + kk];
    }
    #pragma unroll
    for (int r = 0; r < 16; ++r) {
      int idx = (r << 8) + t;
      int kk = idx >> 6, o = idx & 63;
      c1l[kk][o] = c1wT[((k0 + kk) << 6) + o];
    }
    __syncthreads();

    float acc1[4][8];
    #pragma unroll
    for (int i = 0; i < 4; ++i)
      #pragma unroll
      for (int j = 0; j < 8; ++j) acc1[i][j] = 0.f;

    #pragma unroll 2
    for (int c = 0; c < 128; ++c) {
      float xv[8], wv[4];
      uint4 xu = *(const uint4*)&xs[c][tp << 3];
      up2(xu.x, xv[0], xv[1]); up2(xu.y, xv[2], xv[3]);
      up2(xu.z, xv[4], xv[5]); up2(xu.w, xv[6], xv[7]);
      uint2 wu = *(const uint2*)&wch[c][tk << 2];
      up2(wu.x, wv[0], wv[1]); up2(wu.y, wv[2], wv[3]);
      #pragma unroll
      for (int i = 0; i < 4; ++i)
        #pragma unroll
        for (int j = 0; j < 8; ++j)
          acc1[i][j] = fmaf(wv[i], xv[j], acc1[i][j]);
    }

    float4 mb = *(const float4*)&mod_b[k0 + (tk << 2)];
    #pragma unroll
    for (int i = 0; i < 4; ++i) {
      float mbv = ((const float*)&mb)[i];
      float m[8];
      #pragma unroll
      for (int j = 0; j < 8; ++j) {
        float z = acc1[i][j] * rnv[j] + mbv;
        m[j] = 1.f / (1.f + __expf(-z));
      }
      uint4 st;
      st.x = pk2(m[0], m[1]); st.y = pk2(m[2], m[3]);
      st.z = pk2(m[4], m[5]); st.w = pk2(m[6], m[7]);
      *(uint4*)&modbuf[(tk << 2) + i][tp << 3] = st;
    }
    __syncthreads();

    #pragma unroll 2
    for (int kk = 0; kk < 64; ++kk) {
      float mv[8], cv[4];
      uint4 mu = *(const uint4*)&modbuf[kk][tp << 3];
      up2(mu.x, mv[0], mv[1]); up2(mu.y, mv[2], mv[3]);
      up2(mu.z, mv[4], mv[5]); up2(mu.w, mv[6], mv[7]);
      uint2 cu = *(const uint2*)&c1l[kk][tk << 2];
      up2(cu.x, cv[0], cv[1]); up2(cu.y, cv[2], cv[3]);
      #pragma unroll
      for (int i = 0; i < 4; ++i)
        #pragma unroll
        for (int j = 0; j < 8; ++j)
          acc2[i][j] = fmaf(cv[i], mv[j], acc2[i][j]);
    }
  }

  __syncthreads();
  #pragma unroll
  for (int r = 0; r < 32; ++r) {
    int idx = (r << 8) + t;
    int c = idx >> 6, o = idx & 63;
    wch[c][o] = c2T[(c << 6) + o];
  }
  __syncthreads();

  float acc3[4][8];
  #pragma unroll
  for (int i = 0; i < 4; ++i)
    #pragma unroll
    for (int j = 0; j < 8; ++j) acc3[i][j] = 0.f;

  #pragma unroll 2
  for (int c = 0; c < 128; ++c) {
    float xv[8], wv[4];
    uint4 xu = *(const uint4*)&xs[c][tp << 3];
    up2(xu.x, xv[0], xv[1]); up2(xu.y, xv[2], xv[3]);
    up2(xu.z, xv[4], xv[5]); up2(xu.w, xv[6], xv[7]);
    uint2 wu = *(const uint2*)&wch[c][tk << 2];
    up2(wu.x, wv[0], wv[1]); up2(wu.y, wv[2], wv[3]);
    #pragma unroll
    for (int i = 0; i < 4; ++i)
      #pragma unroll
      for (int j = 0; j < 8; ++j)
        acc3[i][j] = fmaf(wv[i], xv[j], acc3[i][j]);
  }

  float4 c1b = *(const float4*)&conv1_b[tk << 2];
  float4 c2b = *(const float4*)&conv2_b[tk << 2];
  size_t base = ((size_t)b << 21) + (size_t)hw0 + (tp << 3);
  #pragma unroll
  for (int i = 0; i < 4; ++i) {
    int o = (tk << 2) + i;
    float ob = ((const float*)&c1b)[i];
    float* p0 = Sn + base + ((size_t)o << 14);
    float4 v0 = { acc2[i][0] + ob, acc2[i][1] + ob, acc2[i][2] + ob, acc2[i][3] + ob };
    float4 v1 = { acc2[i][4] + ob, acc2[i][5] + ob, acc2[i][6] + ob, acc2[i][7] + ob };
    *(float4*)p0 = v0; *(float4*)(p0 + 4) = v1;
    float sb = ((const float*)&c2b)[i];
    float* p1 = Sn + base + ((size_t)(o + 64) << 14);
    float4 u0 = { rnv[0]*acc3[i][0] + sb, rnv[1]*acc3[i][1] + sb,
                  rnv[2]*acc3[i][2] + sb, rnv[3]*acc3[i][3] + sb };
    float4 u1 = { rnv[4]*acc3[i][4] + sb, rnv[5]*acc3[i][5] + sb,
                  rnv[6]*acc3[i][6] + sb, rnv[7]*acc3[i][7] + sb };
    *(float4*)p1 = u0; *(float4*)(p1 + 4) = u1;
  }
}

// ---------------- kernel B: PatchEmbed (4x4/s4 conv + LN) -> f [4096][128] ----
__global__ __launch_bounds__(128) void k_pembed(
    const float* __restrict__ Sn, const u16* __restrict__ pewT,
    const float* __restrict__ pe_b, const float* __restrict__ pe_g,
    const float* __restrict__ pe_beta, float* __restrict__ f)
{
  __shared__ float pat[8][2048];
  __shared__ float fln[8][128];
  __shared__ float pm[8][16], pv[8][16], ms[8], rs[8];
  const int t = threadIdx.x, bx = blockIdx.x;
  const int b = bx >> 7, rem = bx & 127;
  const int ph = rem >> 2, pw0 = (rem & 3) << 3;

  for (int r = 0; r < 128; ++r) {
    int e = (r << 7) + t;
    int row = e >> 5, q32 = e & 31;
    int c = row >> 2, p = row & 3;
    float v = Sn[((size_t)((b * 128 + c) * 128 + (ph * 4 + p))) * 128 + pw0 * 4 + q32];
    pat[q32 >> 2][c * 16 + p * 4 + (q32 & 3)] = v;
  }
  __syncthreads();

  float acc[8];
  #pragma unroll
  for (int j = 0; j < 8; ++j) acc[j] = 0.f;
  for (int idx = 0; idx < 2048; idx += 4) {
    float w0 = b2f(pewT[(size_t)(idx + 0) * 128 + t]);
    float w1 = b2f(pewT[(size_t)(idx + 1) * 128 + t]);
    float w2 = b2f(pewT[(size_t)(idx + 2) * 128 + t]);
    float w3 = b2f(pewT[(size_t)(idx + 3) * 128 + t]);
    #pragma unroll
    for (int j = 0; j < 8; ++j) {
      float4 p4 = *(const float4*)&pat[j][idx];
      acc[j] = fmaf(p4.x, w0, acc[j]);
      acc[j] = fmaf(p4.y, w1, acc[j]);
      acc[j] = fmaf(p4.z, w2, acc[j]);
      acc[j] = fmaf(p4.w, w3, acc[j]);
    }
  }
  float pb = pe_b[t];
  #pragma unroll
  for (int j = 0; j < 8; ++j) fln[j][t] = acc[j] + pb;
  __syncthreads();
  {
    int j = t >> 4, l = t & 15;
    float s1 = 0.f, s2 = 0.f;
    #pragma unroll
    for (int i = 0; i < 8; ++i) { float v = fln[j][l * 8 + i]; s1 += v; s2 += v * v; }
    pm[j][l] = s1; pv[j][l] = s2;
  }
  __syncthreads();
  if (t < 8) {
    float s1 = 0.f, s2 = 0.f;
    #pragma unroll
    for (int i = 0; i < 16; ++i) { s1 += pm[t][i]; s2 += pv[t][i]; }
    float m = s1 * (1.f / 128.f);
    float var = s2 * (1.f / 128.f) - m * m;
    ms[t] = m; rs[t] = rsqrtf(var + 1e-5f);
  }
  __syncthreads();
  int pbase = (b * 32 + ph) * 32 + pw0;
  float g = pe_g[t], be = pe_beta[t];
  #pragma unroll
  for (int j = 0; j < 8; ++j) {
    float v = (fln[j][t] - ms[j]) * rs[j] * g + be;
    f[(size_t)(pbase + j) * 128 + t] = v;
  }
}

// ---------------- kernel C: PatchExpand + LN(32) + up-proj -> M1 NHWC -------
__global__ __launch_bounds__(128) void k_expand(
    const float* __restrict__ f, const float* __restrict__ exp_w,
    const float* __restrict__ fin_g, const float* __restrict__ fin_b,
    const float* __restrict__ up_w, const float* __restrict__ up_b,
    float* __restrict__ M1)
{
  __shared__ float fr[4][128];
  __shared__ float fe[4][512];
  __shared__ float sm[64], sr[64];
  const int t = threadIdx.x, bx = blockIdx.x;
  const int b = bx >> 8, rem = bx & 255;
  const int ph = rem >> 3, pw0 = (rem & 7) << 2;
  const int pbase = (b * 32 + ph) * 32 + pw0;

  #pragma unroll
  for (int j = 0; j < 4; ++j) fr[j][t] = f[(size_t)(pbase + j) * 128 + t];
  __syncthreads();

  float acc[4][4];
  #pragma unroll
  for (int i = 0; i < 4; ++i)
    #pragma unroll
    for (int j = 0; j < 4; ++j) acc[i][j] = 0.f;
  for (int c = 0; c < 128; ++c) {
    float f0 = fr[0][c], f1 = fr[1][c], f2 = fr[2][c], f3 = fr[3][c];
    #pragma unroll
    for (int i = 0; i < 4; ++i) {
      float w = exp_w[(size_t)c * 512 + (i << 7) + t];
      acc[i][0] = fmaf(f0, w, acc[i][0]);
      acc[i][1] = fmaf(f1, w, acc[i][1]);
      acc[i][2] = fmaf(f2, w, acc[i][2]);
      acc[i][3] = fmaf(f3, w, acc[i][3]);
    }
  }
  #pragma unroll
  for (int i = 0; i < 4; ++i)
    #pragma unroll
    for (int pp = 0; pp < 4; ++pp) fe[pp][(i << 7) + t] = acc[i][pp];
  __syncthreads();

  if (t < 64) {
    int pp = t >> 4, sp = t & 15;
    float s1 = 0.f, s2 = 0.f;
    for (int i = 0; i < 32; ++i) {
      float v = fe[pp][sp * 32 + ((t + i) & 31)];
      s1 += v; s2 += v * v;
    }
    float m = s1 * (1.f / 32.f);
    float var = s2 * (1.f / 32.f) - m * m;
    sm[t] = m; sr[t] = rsqrtf(var + 1e-5f);
  }
  __syncthreads();
  #pragma unroll
  for (int r = 0; r < 16; ++r) {
    int idx = (r << 7) + t;
    int pp = idx >> 9, j = idx & 511;
    int gi = idx >> 5, cc = idx & 31;
    float v = fe[pp][j];
    fe[pp][j] = (v - sm[gi]) * sr[gi] * fin_g[cc] + fin_b[cc];
  }
  __syncthreads();

  float uw[32];
  #pragma unroll
  for (int i = 0; i < 32; i += 4) {
    float4 u4 = *(const float4*)&up_w[t * 32 + i];
    uw[i] = u4.x; uw[i + 1] = u4.y; uw[i + 2] = u4.z; uw[i + 3] = u4.w;
  }
  float ub = up_b[t];
  for (int pp = 0; pp < 4; ++pp) {
    for (int sp = 0; sp < 16; ++sp) {
      int p = sp >> 2, q = sp & 3;
      float s = ub;
      #pragma unroll
      for (int cc = 0; cc < 32; ++cc) s = fmaf(fe[pp][sp * 32 + cc], uw[cc], s);
      M1[(((size_t)(b * 128 + ph * 4 + p)) * 128 + ((pw0 + pp) * 4 + q)) * 128 + t] = s;
    }
  }
}

// ---------------- kernel D: Xn = fwt0*(query@WpreT) + fwt1*M1, NHWC bf16 ----
__global__ __launch_bounds__(256) void k_wf(
    const float* __restrict__ Q, const u16* __restrict__ wpreT,
    const float* __restrict__ M1, const float* __restrict__ w2,
    u16* __restrict__ Xn)
{
  __shared__ u16 qs[128][136];
  __shared__ u16 wl[128][136];
  const int t = threadIdx.x, bx = blockIdx.x;
  const int b = bx >> 7;
  const int hw0 = (bx & 127) << 7;
  {
    const int pix = t & 127, ch = t >> 7;
    const float* Qp = Q + ((size_t)b << 21) + (size_t)hw0 + pix;
    #pragma unroll 8
    for (int cc = 0; cc < 64; ++cc) {
      int c = (cc << 1) + ch;
      qs[c][pix] = f2b(Qp[(size_t)c << 14]);
    }
    #pragma unroll
    for (int r = 0; r < 64; ++r) {
      int idx = (r << 8) + t;
      int c = idx >> 7, o = idx & 127;
      wl[c][o] = wpreT[(c << 7) + o];
    }
  }
  __syncthreads();
  const int to = t >> 4, tp = t & 15;
  float acc[8][8];
  #pragma unroll
  for (int i = 0; i < 8; ++i)
    #pragma unroll
    for (int j = 0; j < 8; ++j) acc[i][j] = 0.f;

  #pragma unroll 2
  for (int c = 0; c < 128; ++c) {
    float wv[8], qv[8];
    uint4 wu = *(const uint4*)&wl[c][to << 3];
    up2(wu.x, wv[0], wv[1]); up2(wu.y, wv[2], wv[3]);
    up2(wu.z, wv[4], wv[5]); up2(wu.w, wv[6], wv[7]);
    uint4 qu = *(const uint4*)&qs[c][tp << 3];
    up2(qu.x, qv[0], qv[1]); up2(qu.y, qv[2], qv[3]);
    up2(qu.z, qv[4], qv[5]); up2(qu.w, qv[6], qv[7]);
    #pragma unroll
    for (int i = 0; i < 8; ++i)
      #pragma unroll
      for (int j = 0; j < 8; ++j)
        acc[i][j] = fmaf(wv[i], qv[j], acc[i][j]);
  }
  float a0 = fmaxf(w2[0], 0.f), a1 = fmaxf(w2[1], 0.f);
  float inv = 1.f / (a0 + a1 + 1e-8f);
  float f0 = a0 * inv, f1 = a1 * inv;
  const int o0 = to << 3, p0 = tp << 3;
  #pragma unroll
  for (int j = 0; j < 8; ++j) {
    const float* mp = M1 + (((size_t)(b << 14) + hw0 + p0 + j) << 7) + o0;
    float4 u = *(const float4*)mp, v = *(const float4*)(mp + 4);
    float x0 = f0 * acc[0][j] + f1 * u.x;
    float x1 = f0 * acc[1][j] + f1 * u.y;
    float x2 = f0 * acc[2][j] + f1 * u.z;
    float x3 = f0 * acc[3][j] + f1 * u.w;
    float x4 = f0 * acc[4][j] + f1 * v.x;
    float x5 = f0 * acc[5][j] + f1 * v.y;
    float x6 = f0 * acc[6][j] + f1 * v.z;
    float x7 = f0 * acc[7][j] + f1 * v.w;
    uint4 st = { pk2(x0, x1), pk2(x2, x3), pk2(x4, x5), pk2(x6, x7) };
    *(uint4*)&Xn[(((size_t)(b << 14) + hw0 + p0 + j) << 7) + o0] = st;
  }
}

// ---------------- kernel E: 3x3 conv (MFMA implicit GEMM) + BN + ReLU6 ------
// Block: 8x8 output pixels x 128 o. 256 threads = 4 waves; wave w owns
// n-tiles {2w,2w+1} (o range w*32..w*32+31) and all 4 m-tiles (16 px each).
// A (im2col) from swizzled LDS tile 10x10x128 bf16; B (weights) streamed
// from L2 in prepacked fragment order.
__global__ __launch_bounds__(256) void k_conv3(
    const u16* __restrict__ Xn, const u16* __restrict__ wpk,
    const float* __restrict__ bnb, float* __restrict__ out)
{
  __shared__ u16 it[12800];   // 100 rows x 128 ic, XOR-swizzled
  const int t = threadIdx.x, bx = blockIdx.x;
  const int b = bx >> 8, rem = bx & 255;
  const int ty8 = (rem >> 4) << 3, tx8 = (rem & 15) << 3;
  const int y0 = ty8 - 1, x0 = tx8 - 1;

  // stage input tile (zero-padded), swizzle: elem ^= (ri&7)<<3
  for (int idx = t; idx < 1600; idx += 256) {
    int ri = idx >> 4, cc = idx & 15;
    int gy = y0 + ri / 10, gx = x0 + ri % 10;
    uint4 v = {0u, 0u, 0u, 0u};
    if (gy >= 0 && gy < 128 && gx >= 0 && gx < 128)
      v = *(const uint4*)&Xn[(((size_t)(b << 14) + (gy << 7) + gx) << 7) + (cc << 3)];
    int e = (ri << 7) + (cc << 3);
    e ^= (ri & 7) << 3;
    *(uint4*)&it[e] = v;
  }
  __syncthreads();

  const int w = t >> 6, l = t & 63;
  const int g = l >> 4, cl = l & 15;

  f32x4 acc[4][2];
  #pragma unroll
  for (int m = 0; m < 4; ++m)
    #pragma unroll
    for (int nn = 0; nn < 2; ++nn)
      acc[m][nn] = (f32x4){0.f, 0.f, 0.f, 0.f};

  // per-lane pixel for each m-tile
  int ri0[4];
  #pragma unroll
  for (int m = 0; m < 4; ++m) {
    int p = (m << 4) + cl;
    ri0[m] = (p >> 3) * 10 + (p & 7);
  }

  for (int ks = 0; ks < 4; ++ks) {
    #pragma unroll
    for (int tap = 0; tap < 9; ++tap) {
      const int dy = tap / 3, dx = tap % 3;
      bf16x8 A[4];
      #pragma unroll
      for (int m = 0; m < 4; ++m) {
        int ri = ri0[m] + dy * 10 + dx;
        int e = (ri << 7) + (ks << 5) + (g << 3);
        e ^= (ri & 7) << 3;
        A[m] = *(const bf16x8*)&it[e];
      }
      #pragma unroll
      for (int nn = 0; nn < 2; ++nn) {
        int n = (w << 1) + nn;
        bf16x8 B = *(const bf16x8*)&wpk[((((ks * 9 + tap) << 3) + n) << 9) + (l << 3)];
        #pragma unroll
        for (int m = 0; m < 4; ++m)
          acc[m][nn] = __builtin_amdgcn_mfma_f32_16x16x32_bf16(A[m], B, acc[m][nn], 0, 0, 0);
      }
    }
  }

  // epilogue: lane holds, per (m,nn): o = n*16+cl, pixels p = m*16+g*4+r
  #pragma unroll
  for (int m = 0; m < 4; ++m) {
    int p = (m << 4) + (g << 2);
    int py = p >> 3, px = p & 7;
    #pragma unroll
    for (int nn = 0; nn < 2; ++nn) {
      int n = (w << 1) + nn;
      int o = (n << 4) + cl;
      float bb = bnb[o];
      f32x4 a = acc[m][nn];
      float4 v = { fminf(fmaxf(a[0] + bb, 0.f), 6.f),
                   fminf(fmaxf(a[1] + bb, 0.f), 6.f),
                   fminf(fmaxf(a[2] + bb, 0.f), 6.f),
                   fminf(fmaxf(a[3] + bb, 0.f), 6.f) };
      *(float4*)&out[((size_t)((b << 7) + o) << 14) + ((ty8 + py) << 7) + tx8 + px] = v;
    }
  }
}

extern "C" void kernel_launch(void* const* d_in, const int* in_sizes, int n_in,
                              void* d_out, int out_size, void* d_ws, size_t ws_size,
                              hipStream_t stream) {
  const float* Structure = (const float*)d_in[0];
  const float* query     = (const float*)d_in[1];
  const float* m_items   = (const float*)d_in[2];
  const float* mod_w     = (const float*)d_in[3];
  const float* mod_b     = (const float*)d_in[4];
  const float* conv1_w   = (const float*)d_in[5];
  const float* conv1_b   = (const float*)d_in[6];
  const float* conv2_w   = (const float*)d_in[7];
  const float* conv2_b   = (const float*)d_in[8];
  const float* pe_w      = (const float*)d_in[9];
  const float* pe_b      = (const float*)d_in[10];
  const float* pe_g      = (const float*)d_in[11];
  const float* pe_beta   = (const float*)d_in[12];
  const float* exp_w     = (const float*)d_in[13];
  const float* fin_g     = (const float*)d_in[14];
  const float* fin_b     = (const float*)d_in[15];
  const float* up_w      = (const float*)d_in[16];
  const float* up_b      = (const float*)d_in[17];
  const float* wf_w2     = (const float*)d_in[18];
  const float* wf_pre_w  = (const float*)d_in[19];
  const float* wf_post_w = (const float*)d_in[20];
  const float* wf_bn_g   = (const float*)d_in[21];
  const float* wf_bn_b   = (const float*)d_in[22];

  char* ws = (char*)d_ws;
  float* Sn = (float*)(ws + 0);              // 33,554,432 B
  float* f  = (float*)(ws + 33554432);       //  2,097,152 B
  float* M1 = (float*)(ws + 35651584);       // 33,554,432 B (NHWC)
  u16*   Xn = (u16*)(ws + 0);                // alias Sn (dead after k_pembed), 16.8 MB bf16 NHWC
  u16* modwT  = (u16*)(ws + 69206016);
  u16* c1wT   = (u16*)(ws + 69369856);
  u16* c2T    = (u16*)(ws + 69451776);
  u16* wpreT  = (u16*)(ws + 69468160);
  u16* wpk    = (u16*)(ws + 69500928);
  u16* pewT   = (u16*)(ws + 69795840);       // end at 70,320,128 B

  k_prep<<<2176, 256, 0, stream>>>(mod_w, conv1_w, m_items, conv2_w, wf_pre_w,
                                   wf_post_w, wf_bn_g, pe_w,
                                   modwT, c1wT, c2T, wpreT, wpk, pewT);
  k_read<<<512, 256, 0, stream>>>(Structure, modwT, c1wT, c2T, mod_b,
                                  conv1_b, conv2_b, Sn);
  k_pembed<<<512, 128, 0, stream>>>(Sn, pewT, pe_b, pe_g, pe_beta, f);
  k_expand<<<1024, 128, 0, stream>>>(f, exp_w, fin_g, fin_b, up_w, up_b, M1);
  k_wf<<<512, 256, 0, stream>>>(query, wpreT, M1, wf_w2, Xn);
  k_conv3<<<1024, 256, 0, stream>>>(Xn, wpk, wf_bn_b, (float*)d_out);
}

// Round 3
// 273.063 us; speedup vs baseline: 2.9109x; 1.8067x over previous
//
#include <hip/hip_runtime.h>

typedef unsigned short u16;
typedef unsigned int u32;
typedef __attribute__((ext_vector_type(8))) short bf16x8;
typedef __attribute__((ext_vector_type(4))) float f32x4;

__device__ __forceinline__ float b2f(u16 h) {
  union { u32 u; float f; } v; v.u = ((u32)h) << 16; return v.f;
}
__device__ __forceinline__ u16 f2b(float x) {
  union { float f; u32 u; } v; v.f = x;
  u32 u = v.u;
  return (u16)((u + 0x7FFFu + ((u >> 16) & 1u)) >> 16);  // RTN-even
}
__device__ __forceinline__ void up2(u32 u, float& lo, float& hi) {
  union { u32 x; float f; } a, b;
  a.x = u << 16; b.x = u & 0xFFFF0000u;
  lo = a.f; hi = b.f;
}
__device__ __forceinline__ u32 pk2(float lo, float hi) {
  return (u32)f2b(lo) | ((u32)f2b(hi) << 16);
}

// ---------------- prep: weight transposes / folds (bf16) ----------------
// wG1  [chan=640][c=128] = mod_w (straight bf16 cast)
// c1wF [o=64][k=640]     = conv1_w[o][k] * m_items[k]
// c2F  [o=64][c=128]     = conv2_w
// wpreT[c][128]          = wf_pre_w[o][c]
// wpk: conv3 weights in MFMA B-fragment order
// pewT [k=2048][128]     = pe_w[o][k]
__global__ __launch_bounds__(256) void k_prep(
    const float* __restrict__ mod_w, const float* __restrict__ conv1_w,
    const float* __restrict__ m_items, const float* __restrict__ conv2_w,
    const float* __restrict__ wf_pre_w, const float* __restrict__ wf_post_w,
    const float* __restrict__ wf_bn_g, const float* __restrict__ pe_w,
    u16* __restrict__ wG1, u16* __restrict__ c1wF, u16* __restrict__ c2F,
    u16* __restrict__ wpreT, u16* __restrict__ wpk, u16* __restrict__ pewT)
{
  int idx = blockIdx.x * 256 + threadIdx.x;
  if (idx < 81920) {
    wG1[idx] = f2b(mod_w[idx]);
  } else if (idx < 122880) {
    int i = idx - 81920; int k = i % 640;
    c1wF[i] = f2b(conv1_w[i] * m_items[k]);
  } else if (idx < 131072) {
    int i = idx - 122880;
    c2F[i] = f2b(conv2_w[i]);
  } else if (idx < 147456) {
    int i = idx - 131072; int c = i >> 7, o = i & 127;
    wpreT[i] = f2b(wf_pre_w[o * 128 + c]);
  } else if (idx < 294912) {
    int i2 = idx - 147456;
    int e = i2 & 7;
    int r = i2 >> 3;
    int lane = r & 63; r >>= 6;
    int n = r & 7; r >>= 3;          // r = ks*9+tap, 0..35
    int tap = r % 9, ks = r / 9;
    int o = (n << 4) + (lane & 15);
    int ic = (ks << 5) + ((lane >> 4) << 3) + e;
    int dy = tap / 3, dx = tap % 3;
    float scale = wf_bn_g[o] * rsqrtf(1.f + 1e-5f);
    wpk[i2] = f2b(wf_post_w[((o * 128 + ic) * 3 + dy) * 3 + dx] * scale);
  } else if (idx < 557056) {
    int i = idx - 294912; int k = i >> 7, o = i & 127;
    pewT[i] = f2b(pe_w[o * 2048 + k]);
  }
}

// ---------------- kernel A: fused read() -> Sn [B,128,H,W], MFMA ----------
// Block = 128 pixels, 256 threads = 4 waves (wave w owns pixels w*32..w*32+31).
// GEMM1 (mod, K=128) swapped: D^T tiles -> per-lane pixel scalar rn, sigmoid,
// pack to swizzled modL[pix][kk]. GEMM2 (K=640 chunked 64) + GEMM3 (conv2).
__global__ __launch_bounds__(256) void k_read(
    const float* __restrict__ S, const u16* __restrict__ wG1,
    const u16* __restrict__ c1wF, const u16* __restrict__ c2F,
    const float* __restrict__ mod_b,
    const float* __restrict__ conv1_b, const float* __restrict__ conv2_b,
    float* __restrict__ Sn)
{
  __shared__ u16 xs[16384];        // [pix=128][c=128] bf16, XOR-swizzled
  __shared__ u16 modL[2][8192];    // [pix=128][kk=64] bf16, XOR-swizzled
  __shared__ float rn[128];
  __shared__ float ps[2][128];
  __shared__ float mbL[640];

  const int t = threadIdx.x;
  const int b = blockIdx.x >> 7;
  const int hw0 = (blockIdx.x & 127) << 7;

  { // stage x (unnormalized bf16) + sumsq
    const int pix = t & 127, ch = t >> 7;   // ch selects c-half
    const float* Sp = S + ((size_t)b << 21) + (size_t)hw0 + pix;
    float ss = 0.f;
    #pragma unroll
    for (int c0 = 0; c0 < 64; c0 += 8) {
      float v[8]; u32 pkv[4];
      #pragma unroll
      for (int j = 0; j < 8; ++j) {
        v[j] = Sp[(size_t)(ch * 64 + c0 + j) << 14];
        ss += v[j] * v[j];
      }
      #pragma unroll
      for (int j = 0; j < 4; ++j) pkv[j] = pk2(v[2 * j], v[2 * j + 1]);
      int e = pix * 256 + (ch * 64 + c0) * 2;
      e ^= (pix & 7) << 4;
      *(uint4*)((char*)xs + e) = *(const uint4*)pkv;
    }
    ps[ch][pix] = ss;
  }
  for (int i = t; i < 640; i += 256) mbL[i] = mod_b[i];
  __syncthreads();
  if (t < 128) rn[t] = 1.f / fmaxf(sqrtf(ps[0][t] + ps[1][t]), 1e-12f);
  __syncthreads();

  const int w = t >> 6, l = t & 63;
  const int g = l >> 4, cl = l & 15;
  const int pxw = w << 5;          // wave pixel base
  const int swz = (cl & 7) << 4;   // XOR swizzle for this lane's pix rows

  float rncol[2] = { rn[pxw + cl], rn[pxw + 16 + cl] };

  f32x4 acc2[2][4];
  #pragma unroll
  for (int pt = 0; pt < 2; ++pt)
    #pragma unroll
    for (int nt = 0; nt < 4; ++nt) acc2[pt][nt] = (f32x4){0.f, 0.f, 0.f, 0.f};

  for (int i = 0; i < 10; ++i) {
    const int n0 = i << 6;
    // prefetch GEMM2 B-fragments (L2-resident) to overlap GEMM1
    bf16x8 bf2[2][4];
    #pragma unroll
    for (int kt = 0; kt < 2; ++kt)
      #pragma unroll
      for (int nt = 0; nt < 4; ++nt)
        bf2[kt][nt] = *(const bf16x8*)&c1wF[(size_t)((nt << 4) + cl) * 640 + n0 + kt * 32 + g * 8];

    // GEMM1: acc1[ct][pt] = W(16 chan x K) x X^T(K x 16 pix), swapped orient
    f32x4 acc1[4][2];
    #pragma unroll
    for (int ct = 0; ct < 4; ++ct)
      #pragma unroll
      for (int pt = 0; pt < 2; ++pt) acc1[ct][pt] = (f32x4){0.f, 0.f, 0.f, 0.f};
    #pragma unroll
    for (int ks = 0; ks < 4; ++ks) {
      bf16x8 xf[2];
      #pragma unroll
      for (int pt = 0; pt < 2; ++pt) {
        int pix = pxw + (pt << 4) + cl;
        int e = (pix * 256 + ks * 64 + g * 16) ^ swz;
        xf[pt] = *(const bf16x8*)((const char*)xs + e);
      }
      #pragma unroll
      for (int ct = 0; ct < 4; ++ct) {
        bf16x8 wf = *(const bf16x8*)&wG1[(size_t)(n0 + (ct << 4) + cl) * 128 + ks * 32 + g * 8];
        acc1[ct][0] = __builtin_amdgcn_mfma_f32_16x16x32_bf16(wf, xf[0], acc1[ct][0], 0, 0, 0);
        acc1[ct][1] = __builtin_amdgcn_mfma_f32_16x16x32_bf16(wf, xf[1], acc1[ct][1], 0, 0, 0);
      }
    }

    // sigmoid((acc*rn)+b) -> bf16 -> modL[i&1] (8B contiguous per lane)
    char* mbuf = (char*)modL[i & 1];
    #pragma unroll
    for (int pt = 0; pt < 2; ++pt) {
      int pix = pxw + (pt << 4) + cl;
      float rv = rncol[pt];
      #pragma unroll
      for (int ct = 0; ct < 4; ++ct) {
        float4 mb4 = *(const float4*)&mbL[n0 + (ct << 4) + (g << 2)];
        f32x4 a = acc1[ct][pt];
        float m[4];
        #pragma unroll
        for (int r = 0; r < 4; ++r) {
          float z = a[r] * rv + ((const float*)&mb4)[r];
          m[r] = __builtin_amdgcn_rcpf(1.f + __expf(-z));
        }
        u32 lo, hi;
        asm("v_cvt_pk_bf16_f32 %0, %1, %2" : "=v"(lo) : "v"(m[0]), "v"(m[1]));
        asm("v_cvt_pk_bf16_f32 %0, %1, %2" : "=v"(hi) : "v"(m[2]), "v"(m[3]));
        int e = (pix * 128 + ct * 32 + g * 8) ^ swz;
        uint2 st = { lo, hi };
        *(uint2*)(mbuf + e) = st;
      }
    }
    __syncthreads();

    // GEMM2: acc2[pt][nt] += mod[pix][kk] x c1wF
    #pragma unroll
    for (int kt = 0; kt < 2; ++kt) {
      bf16x8 af[2];
      #pragma unroll
      for (int pt = 0; pt < 2; ++pt) {
        int pix = pxw + (pt << 4) + cl;
        int e = (pix * 128 + kt * 64 + g * 16) ^ swz;
        af[pt] = *(const bf16x8*)((const char*)mbuf + e);
      }
      #pragma unroll
      for (int nt = 0; nt < 4; ++nt) {
        acc2[0][nt] = __builtin_amdgcn_mfma_f32_16x16x32_bf16(af[0], bf2[kt][nt], acc2[0][nt], 0, 0, 0);
        acc2[1][nt] = __builtin_amdgcn_mfma_f32_16x16x32_bf16(af[1], bf2[kt][nt], acc2[1][nt], 0, 0, 0);
      }
    }
  }

  // GEMM3: Sc = (x @ c2F^T) * rn
  f32x4 acc3[2][4];
  #pragma unroll
  for (int pt = 0; pt < 2; ++pt)
    #pragma unroll
    for (int nt = 0; nt < 4; ++nt) acc3[pt][nt] = (f32x4){0.f, 0.f, 0.f, 0.f};
  #pragma unroll
  for (int ks = 0; ks < 4; ++ks) {
    bf16x8 af[2];
    #pragma unroll
    for (int pt = 0; pt < 2; ++pt) {
      int pix = pxw + (pt << 4) + cl;
      int e = (pix * 256 + ks * 64 + g * 16) ^ swz;
      af[pt] = *(const bf16x8*)((const char*)xs + e);
    }
    #pragma unroll
    for (int nt = 0; nt < 4; ++nt) {
      bf16x8 bfr = *(const bf16x8*)&c2F[(size_t)((nt << 4) + cl) * 128 + ks * 32 + g * 8];
      acc3[0][nt] = __builtin_amdgcn_mfma_f32_16x16x32_bf16(af[0], bfr, acc3[0][nt], 0, 0, 0);
      acc3[1][nt] = __builtin_amdgcn_mfma_f32_16x16x32_bf16(af[1], bfr, acc3[1][nt], 0, 0, 0);
    }
  }

  // epilogue: D col = o = nt*16+cl, rows = pix = pxw+pt*16+g*4+r
  #pragma unroll
  for (int pt = 0; pt < 2; ++pt) {
    int pixr = pxw + (pt << 4) + (g << 2);
    float4 rn4 = *(const float4*)&rn[pixr];
    #pragma unroll
    for (int nt = 0; nt < 4; ++nt) {
      int o = (nt << 4) + cl;
      float b1 = conv1_b[o];
      f32x4 a2 = acc2[pt][nt];
      float4 v0 = { a2[0] + b1, a2[1] + b1, a2[2] + b1, a2[3] + b1 };
      *(float4*)&Sn[((size_t)((b << 7) + o) << 14) + hw0 + pixr] = v0;
      float b2 = conv2_b[o];
      f32x4 a3 = acc3[pt][nt];
      float4 v1 = { a3[0] * rn4.x + b2, a3[1] * rn4.y + b2,
                    a3[2] * rn4.z + b2, a3[3] * rn4.w + b2 };
      *(float4*)&Sn[((size_t)((b << 7) + 64 + o) << 14) + hw0 + pixr] = v1;
    }
  }
}

// ---------------- kernel B: PatchEmbed (4x4/s4 conv + LN) -> f [4096][128] ----
__global__ __launch_bounds__(128) void k_pembed(
    const float* __restrict__ Sn, const u16* __restrict__ pewT,
    const float* __restrict__ pe_b, const float* __restrict__ pe_g,
    const float* __restrict__ pe_beta, float* __restrict__ f)
{
  __shared__ float pat[8][2048];
  __shared__ float fln[8][128];
  __shared__ float pm[8][16], pv[8][16], ms[8], rs[8];
  const int t = threadIdx.x, bx = blockIdx.x;
  const int b = bx >> 7, rem = bx & 127;
  const int ph = rem >> 2, pw0 = (rem & 3) << 3;

  for (int r = 0; r < 128; ++r) {
    int e = (r << 7) + t;
    int row = e >> 5, q32 = e & 31;
    int c = row >> 2, p = row & 3;
    float v = Sn[((size_t)((b * 128 + c) * 128 + (ph * 4 + p))) * 128 + pw0 * 4 + q32];
    pat[q32 >> 2][c * 16 + p * 4 + (q32 & 3)] = v;
  }
  __syncthreads();

  float acc[8];
  #pragma unroll
  for (int j = 0; j < 8; ++j) acc[j] = 0.f;
  for (int idx = 0; idx < 2048; idx += 4) {
    float w0 = b2f(pewT[(size_t)(idx + 0) * 128 + t]);
    float w1 = b2f(pewT[(size_t)(idx + 1) * 128 + t]);
    float w2 = b2f(pewT[(size_t)(idx + 2) * 128 + t]);
    float w3 = b2f(pewT[(size_t)(idx + 3) * 128 + t]);
    #pragma unroll
    for (int j = 0; j < 8; ++j) {
      float4 p4 = *(const float4*)&pat[j][idx];
      acc[j] = fmaf(p4.x, w0, acc[j]);
      acc[j] = fmaf(p4.y, w1, acc[j]);
      acc[j] = fmaf(p4.z, w2, acc[j]);
      acc[j] = fmaf(p4.w, w3, acc[j]);
    }
  }
  float pb = pe_b[t];
  #pragma unroll
  for (int j = 0; j < 8; ++j) fln[j][t] = acc[j] + pb;
  __syncthreads();
  {
    int j = t >> 4, l = t & 15;
    float s1 = 0.f, s2 = 0.f;
    #pragma unroll
    for (int i = 0; i < 8; ++i) { float v = fln[j][l * 8 + i]; s1 += v; s2 += v * v; }
    pm[j][l] = s1; pv[j][l] = s2;
  }
  __syncthreads();
  if (t < 8) {
    float s1 = 0.f, s2 = 0.f;
    #pragma unroll
    for (int i = 0; i < 16; ++i) { s1 += pm[t][i]; s2 += pv[t][i]; }
    float m = s1 * (1.f / 128.f);
    float var = s2 * (1.f / 128.f) - m * m;
    ms[t] = m; rs[t] = rsqrtf(var + 1e-5f);
  }
  __syncthreads();
  int pbase = (b * 32 + ph) * 32 + pw0;
  float g = pe_g[t], be = pe_beta[t];
  #pragma unroll
  for (int j = 0; j < 8; ++j) {
    float v = (fln[j][t] - ms[j]) * rs[j] * g + be;
    f[(size_t)(pbase + j) * 128 + t] = v;
  }
}

// ---------------- kernel C: PatchExpand + LN(32) + up-proj -> M1 NHWC -------
__global__ __launch_bounds__(128) void k_expand(
    const float* __restrict__ f, const float* __restrict__ exp_w,
    const float* __restrict__ fin_g, const float* __restrict__ fin_b,
    const float* __restrict__ up_w, const float* __restrict__ up_b,
    float* __restrict__ M1)
{
  __shared__ float fr[4][128];
  __shared__ float fe[4][512];
  __shared__ float sm[64], sr[64];
  const int t = threadIdx.x, bx = blockIdx.x;
  const int b = bx >> 8, rem = bx & 255;
  const int ph = rem >> 3, pw0 = (rem & 7) << 2;
  const int pbase = (b * 32 + ph) * 32 + pw0;

  #pragma unroll
  for (int j = 0; j < 4; ++j) fr[j][t] = f[(size_t)(pbase + j) * 128 + t];
  __syncthreads();

  float acc[4][4];
  #pragma unroll
  for (int i = 0; i < 4; ++i)
    #pragma unroll
    for (int j = 0; j < 4; ++j) acc[i][j] = 0.f;
  for (int c = 0; c < 128; ++c) {
    float f0 = fr[0][c], f1 = fr[1][c], f2 = fr[2][c], f3 = fr[3][c];
    #pragma unroll
    for (int i = 0; i < 4; ++i) {
      float w = exp_w[(size_t)c * 512 + (i << 7) + t];
      acc[i][0] = fmaf(f0, w, acc[i][0]);
      acc[i][1] = fmaf(f1, w, acc[i][1]);
      acc[i][2] = fmaf(f2, w, acc[i][2]);
      acc[i][3] = fmaf(f3, w, acc[i][3]);
    }
  }
  #pragma unroll
  for (int i = 0; i < 4; ++i)
    #pragma unroll
    for (int pp = 0; pp < 4; ++pp) fe[pp][(i << 7) + t] = acc[i][pp];
  __syncthreads();

  if (t < 64) {
    int pp = t >> 4, sp = t & 15;
    float s1 = 0.f, s2 = 0.f;
    for (int i = 0; i < 32; ++i) {
      float v = fe[pp][sp * 32 + ((t + i) & 31)];
      s1 += v; s2 += v * v;
    }
    float m = s1 * (1.f / 32.f);
    float var = s2 * (1.f / 32.f) - m * m;
    sm[t] = m; sr[t] = rsqrtf(var + 1e-5f);
  }
  __syncthreads();
  #pragma unroll
  for (int r = 0; r < 16; ++r) {
    int idx = (r << 7) + t;
    int pp = idx >> 9, j = idx & 511;
    int gi = idx >> 5, cc = idx & 31;
    float v = fe[pp][j];
    fe[pp][j] = (v - sm[gi]) * sr[gi] * fin_g[cc] + fin_b[cc];
  }
  __syncthreads();

  float uw[32];
  #pragma unroll
  for (int i = 0; i < 32; i += 4) {
    float4 u4 = *(const float4*)&up_w[t * 32 + i];
    uw[i] = u4.x; uw[i + 1] = u4.y; uw[i + 2] = u4.z; uw[i + 3] = u4.w;
  }
  float ub = up_b[t];
  for (int pp = 0; pp < 4; ++pp) {
    for (int sp = 0; sp < 16; ++sp) {
      int p = sp >> 2, q = sp & 3;
      float s = ub;
      #pragma unroll
      for (int cc = 0; cc < 32; ++cc) s = fmaf(fe[pp][sp * 32 + cc], uw[cc], s);
      M1[(((size_t)(b * 128 + ph * 4 + p)) * 128 + ((pw0 + pp) * 4 + q)) * 128 + t] = s;
    }
  }
}

// ---------------- kernel D: Xn = fwt0*(query@WpreT) + fwt1*M1, NHWC bf16 ----
__global__ __launch_bounds__(256) void k_wf(
    const float* __restrict__ Q, const u16* __restrict__ wpreT,
    const float* __restrict__ M1, const float* __restrict__ w2,
    u16* __restrict__ Xn)
{
  __shared__ u16 qs[128][136];
  __shared__ u16 wl[128][136];
  const int t = threadIdx.x, bx = blockIdx.x;
  const int b = bx >> 7;
  const int hw0 = (bx & 127) << 7;
  {
    const int pix = t & 127, ch = t >> 7;
    const float* Qp = Q + ((size_t)b << 21) + (size_t)hw0 + pix;
    #pragma unroll 8
    for (int cc = 0; cc < 64; ++cc) {
      int c = (cc << 1) + ch;
      qs[c][pix] = f2b(Qp[(size_t)c << 14]);
    }
    #pragma unroll
    for (int r = 0; r < 64; ++r) {
      int idx = (r << 8) + t;
      int c = idx >> 7, o = idx & 127;
      wl[c][o] = wpreT[(c << 7) + o];
    }
  }
  __syncthreads();
  const int to = t >> 4, tp = t & 15;
  float acc[8][8];
  #pragma unroll
  for (int i = 0; i < 8; ++i)
    #pragma unroll
    for (int j = 0; j < 8; ++j) acc[i][j] = 0.f;

  #pragma unroll 2
  for (int c = 0; c < 128; ++c) {
    float wv[8], qv[8];
    uint4 wu = *(const uint4*)&wl[c][to << 3];
    up2(wu.x, wv[0], wv[1]); up2(wu.y, wv[2], wv[3]);
    up2(wu.z, wv[4], wv[5]); up2(wu.w, wv[6], wv[7]);
    uint4 qu = *(const uint4*)&qs[c][tp << 3];
    up2(qu.x, qv[0], qv[1]); up2(qu.y, qv[2], qv[3]);
    up2(qu.z, qv[4], qv[5]); up2(qu.w, qv[6], qv[7]);
    #pragma unroll
    for (int i = 0; i < 8; ++i)
      #pragma unroll
      for (int j = 0; j < 8; ++j)
        acc[i][j] = fmaf(wv[i], qv[j], acc[i][j]);
  }
  float a0 = fmaxf(w2[0], 0.f), a1 = fmaxf(w2[1], 0.f);
  float inv = 1.f / (a0 + a1 + 1e-8f);
  float f0 = a0 * inv, f1 = a1 * inv;
  const int o0 = to << 3, p0 = tp << 3;
  #pragma unroll
  for (int j = 0; j < 8; ++j) {
    const float* mp = M1 + (((size_t)(b << 14) + hw0 + p0 + j) << 7) + o0;
    float4 u = *(const float4*)mp, v = *(const float4*)(mp + 4);
    float x0 = f0 * acc[0][j] + f1 * u.x;
    float x1 = f0 * acc[1][j] + f1 * u.y;
    float x2 = f0 * acc[2][j] + f1 * u.z;
    float x3 = f0 * acc[3][j] + f1 * u.w;
    float x4 = f0 * acc[4][j] + f1 * v.x;
    float x5 = f0 * acc[5][j] + f1 * v.y;
    float x6 = f0 * acc[6][j] + f1 * v.z;
    float x7 = f0 * acc[7][j] + f1 * v.w;
    uint4 st = { pk2(x0, x1), pk2(x2, x3), pk2(x4, x5), pk2(x6, x7) };
    *(uint4*)&Xn[(((size_t)(b << 14) + hw0 + p0 + j) << 7) + o0] = st;
  }
}

// ---------------- kernel E: 3x3 conv (MFMA implicit GEMM) + BN + ReLU6 ------
__global__ __launch_bounds__(256) void k_conv3(
    const u16* __restrict__ Xn, const u16* __restrict__ wpk,
    const float* __restrict__ bnb, float* __restrict__ out)
{
  __shared__ u16 it[12800];   // 100 rows x 128 ic, XOR-swizzled
  const int t = threadIdx.x, bx = blockIdx.x;
  const int b = bx >> 8, rem = bx & 255;
  const int ty8 = (rem >> 4) << 3, tx8 = (rem & 15) << 3;
  const int y0 = ty8 - 1, x0 = tx8 - 1;

  for (int idx = t; idx < 1600; idx += 256) {
    int ri = idx >> 4, cc = idx & 15;
    int gy = y0 + ri / 10, gx = x0 + ri % 10;
    uint4 v = {0u, 0u, 0u, 0u};
    if (gy >= 0 && gy < 128 && gx >= 0 && gx < 128)
      v = *(const uint4*)&Xn[(((size_t)(b << 14) + (gy << 7) + gx) << 7) + (cc << 3)];
    int e = (ri << 7) + (cc << 3);
    e ^= (ri & 7) << 3;
    *(uint4*)&it[e] = v;
  }
  __syncthreads();

  const int w = t >> 6, l = t & 63;
  const int g = l >> 4, cl = l & 15;

  f32x4 acc[4][2];
  #pragma unroll
  for (int m = 0; m < 4; ++m)
    #pragma unroll
    for (int nn = 0; nn < 2; ++nn)
      acc[m][nn] = (f32x4){0.f, 0.f, 0.f, 0.f};

  int ri0[4];
  #pragma unroll
  for (int m = 0; m < 4; ++m) {
    int p = (m << 4) + cl;
    ri0[m] = (p >> 3) * 10 + (p & 7);
  }

  for (int ks = 0; ks < 4; ++ks) {
    #pragma unroll
    for (int tap = 0; tap < 9; ++tap) {
      const int dy = tap / 3, dx = tap % 3;
      bf16x8 A[4];
      #pragma unroll
      for (int m = 0; m < 4; ++m) {
        int ri = ri0[m] + dy * 10 + dx;
        int e = (ri << 7) + (ks << 5) + (g << 3);
        e ^= (ri & 7) << 3;
        A[m] = *(const bf16x8*)&it[e];
      }
      #pragma unroll
      for (int nn = 0; nn < 2; ++nn) {
        int n = (w << 1) + nn;
        bf16x8 B = *(const bf16x8*)&wpk[((((ks * 9 + tap) << 3) + n) << 9) + (l << 3)];
        #pragma unroll
        for (int m = 0; m < 4; ++m)
          acc[m][nn] = __builtin_amdgcn_mfma_f32_16x16x32_bf16(A[m], B, acc[m][nn], 0, 0, 0);
      }
    }
  }

  #pragma unroll
  for (int m = 0; m < 4; ++m) {
    int p = (m << 4) + (g << 2);
    int py = p >> 3, px = p & 7;
    #pragma unroll
    for (int nn = 0; nn < 2; ++nn) {
      int n = (w << 1) + nn;
      int o = (n << 4) + cl;
      float bb = bnb[o];
      f32x4 a = acc[m][nn];
      float4 v = { fminf(fmaxf(a[0] + bb, 0.f), 6.f),
                   fminf(fmaxf(a[1] + bb, 0.f), 6.f),
                   fminf(fmaxf(a[2] + bb, 0.f), 6.f),
                   fminf(fmaxf(a[3] + bb, 0.f), 6.f) };
      *(float4*)&out[((size_t)((b << 7) + o) << 14) + ((ty8 + py) << 7) + tx8 + px] = v;
    }
  }
}

extern "C" void kernel_launch(void* const* d_in, const int* in_sizes, int n_in,
                              void* d_out, int out_size, void* d_ws, size_t ws_size,
                              hipStream_t stream) {
  const float* Structure = (const float*)d_in[0];
  const float* query     = (const float*)d_in[1];
  const float* m_items   = (const float*)d_in[2];
  const float* mod_w     = (const float*)d_in[3];
  const float* mod_b     = (const float*)d_in[4];
  const float* conv1_w   = (const float*)d_in[5];
  const float* conv1_b   = (const float*)d_in[6];
  const float* conv2_w   = (const float*)d_in[7];
  const float* conv2_b   = (const float*)d_in[8];
  const float* pe_w      = (const float*)d_in[9];
  const float* pe_b      = (const float*)d_in[10];
  const float* pe_g      = (const float*)d_in[11];
  const float* pe_beta   = (const float*)d_in[12];
  const float* exp_w     = (const float*)d_in[13];
  const float* fin_g     = (const float*)d_in[14];
  const float* fin_b     = (const float*)d_in[15];
  const float* up_w      = (const float*)d_in[16];
  const float* up_b      = (const float*)d_in[17];
  const float* wf_w2     = (const float*)d_in[18];
  const float* wf_pre_w  = (const float*)d_in[19];
  const float* wf_post_w = (const float*)d_in[20];
  const float* wf_bn_g   = (const float*)d_in[21];
  const float* wf_bn_b   = (const float*)d_in[22];

  char* ws = (char*)d_ws;
  float* Sn = (float*)(ws + 0);              // 33,554,432 B
  float* f  = (float*)(ws + 33554432);       //  2,097,152 B
  float* M1 = (float*)(ws + 35651584);       // 33,554,432 B (NHWC)
  u16*   Xn = (u16*)(ws + 0);                // alias Sn (dead after k_pembed)
  u16* wG1   = (u16*)(ws + 69206016);        // 163,840 B
  u16* c1wF  = (u16*)(ws + 69369856);        //  81,920 B
  u16* c2F   = (u16*)(ws + 69451776);        //  16,384 B
  u16* wpreT = (u16*)(ws + 69468160);        //  32,768 B
  u16* wpk   = (u16*)(ws + 69500928);        // 294,912 B
  u16* pewT  = (u16*)(ws + 69795840);        // end 70,320,128 B

  k_prep<<<2176, 256, 0, stream>>>(mod_w, conv1_w, m_items, conv2_w, wf_pre_w,
                                   wf_post_w, wf_bn_g, pe_w,
                                   wG1, c1wF, c2F, wpreT, wpk, pewT);
  k_read<<<512, 256, 0, stream>>>(Structure, wG1, c1wF, c2F, mod_b,
                                  conv1_b, conv2_b, Sn);
  k_pembed<<<512, 128, 0, stream>>>(Sn, pewT, pe_b, pe_g, pe_beta, f);
  k_expand<<<1024, 128, 0, stream>>>(f, exp_w, fin_g, fin_b, up_w, up_b, M1);
  k_wf<<<512, 256, 0, stream>>>(query, wpreT, M1, wf_w2, Xn);
  k_conv3<<<1024, 256, 0, stream>>>(Xn, wpk, wf_bn_b, (float*)d_out);
}

// Round 4
// 227.342 us; speedup vs baseline: 3.4963x; 1.2011x over previous
//
#include <hip/hip_runtime.h>

typedef unsigned short u16;
typedef unsigned int u32;
typedef __attribute__((ext_vector_type(8))) short bf16x8;
typedef __attribute__((ext_vector_type(4))) float f32x4;

__device__ __forceinline__ float b2f(u16 h) {
  union { u32 u; float f; } v; v.u = ((u32)h) << 16; return v.f;
}
__device__ __forceinline__ u16 f2b(float x) {
  union { float f; u32 u; } v; v.f = x;
  u32 u = v.u;
  return (u16)((u + 0x7FFFu + ((u >> 16) & 1u)) >> 16);  // RTN-even
}
__device__ __forceinline__ void up2(u32 u, float& lo, float& hi) {
  union { u32 x; float f; } a, b;
  a.x = u << 16; b.x = u & 0xFFFF0000u;
  lo = a.f; hi = b.f;
}
__device__ __forceinline__ u32 pk2(float lo, float hi) {
  return (u32)f2b(lo) | ((u32)f2b(hi) << 16);
}

// ---------------- prep: weight transposes / folds (bf16) ----------------
// wG1  [chan=640][c=128] = mod_w
// c1wF [o=64][k=640]     = conv1_w[o][k] * m_items[k]
// c2F  [o=64][c=128]     = conv2_w
// wpreT[c][128]          = wf_pre_w[o][c]
// wpk: conv3 weights in MFMA B-fragment order
// pewB: patch-embed weights in MFMA B-fragment order:
//   pewB[((gks*8+n)*64+lane)*8+i] = pe_w[o=n*16+(lane&15)][k=gks*32+(lane>>4)*8+i]
__global__ __launch_bounds__(256) void k_prep(
    const float* __restrict__ mod_w, const float* __restrict__ conv1_w,
    const float* __restrict__ m_items, const float* __restrict__ conv2_w,
    const float* __restrict__ wf_pre_w, const float* __restrict__ wf_post_w,
    const float* __restrict__ wf_bn_g, const float* __restrict__ pe_w,
    u16* __restrict__ wG1, u16* __restrict__ c1wF, u16* __restrict__ c2F,
    u16* __restrict__ wpreT, u16* __restrict__ wpk, u16* __restrict__ pewB)
{
  int idx = blockIdx.x * 256 + threadIdx.x;
  if (idx < 81920) {
    wG1[idx] = f2b(mod_w[idx]);
  } else if (idx < 122880) {
    int i = idx - 81920; int k = i % 640;
    c1wF[i] = f2b(conv1_w[i] * m_items[k]);
  } else if (idx < 131072) {
    int i = idx - 122880;
    c2F[i] = f2b(conv2_w[i]);
  } else if (idx < 147456) {
    int i = idx - 131072; int c = i >> 7, o = i & 127;
    wpreT[i] = f2b(wf_pre_w[o * 128 + c]);
  } else if (idx < 294912) {
    int i2 = idx - 147456;
    int e = i2 & 7;
    int r = i2 >> 3;
    int lane = r & 63; r >>= 6;
    int n = r & 7; r >>= 3;          // r = ks*9+tap, 0..35
    int tap = r % 9, ks = r / 9;
    int o = (n << 4) + (lane & 15);
    int ic = (ks << 5) + ((lane >> 4) << 3) + e;
    int dy = tap / 3, dx = tap % 3;
    float scale = wf_bn_g[o] * rsqrtf(1.f + 1e-5f);
    wpk[i2] = f2b(wf_post_w[((o * 128 + ic) * 3 + dy) * 3 + dx] * scale);
  } else if (idx < 557056) {
    int i = idx - 294912;            // 0..262143
    int e = i & 7;
    int r = i >> 3;
    int lane = r & 63; r >>= 6;
    int n = r & 7;
    int gks = r >> 3;                // 0..63
    int o = (n << 4) + (lane & 15);
    int k = (gks << 5) + ((lane >> 4) << 3) + e;
    pewB[i] = f2b(pe_w[o * 2048 + k]);
  }
}

// ---------------- kernel A: fused read() -> Snp [4096 patches][2048] bf16 ---
// Block = one image row (128 px), 256 threads = 4 waves.
// GEMM1 (mod, K=128) swapped orient; sigmoid -> swizzled LDS; GEMM2 (K=640);
// GEMM3 (conv2). Epilogue packs directly into patch-major im2col bf16 layout.
__global__ __launch_bounds__(256) void k_read(
    const float* __restrict__ S, const u16* __restrict__ wG1,
    const u16* __restrict__ c1wF, const u16* __restrict__ c2F,
    const float* __restrict__ mod_b,
    const float* __restrict__ conv1_b, const float* __restrict__ conv2_b,
    u16* __restrict__ Snp)
{
  __shared__ u16 xs[16384];        // [pix=128][c=128] bf16, XOR-swizzled
  __shared__ u16 modL[2][8192];    // [pix=128][kk=64] bf16, XOR-swizzled
  __shared__ float rn[128];
  __shared__ float ps[2][128];
  __shared__ float mbL[640];

  const int t = threadIdx.x;
  const int b = blockIdx.x >> 7;
  const int y = blockIdx.x & 127;
  const int hw0 = y << 7;

  { // stage x (unnormalized bf16) + sumsq
    const int pix = t & 127, ch = t >> 7;
    const float* Sp = S + ((size_t)b << 21) + (size_t)hw0 + pix;
    float ss = 0.f;
    #pragma unroll
    for (int c0 = 0; c0 < 64; c0 += 8) {
      float v[8]; u32 pkv[4];
      #pragma unroll
      for (int j = 0; j < 8; ++j) {
        v[j] = Sp[(size_t)(ch * 64 + c0 + j) << 14];
        ss += v[j] * v[j];
      }
      #pragma unroll
      for (int j = 0; j < 4; ++j) pkv[j] = pk2(v[2 * j], v[2 * j + 1]);
      int e = pix * 256 + (ch * 64 + c0) * 2;
      e ^= (pix & 7) << 4;
      *(uint4*)((char*)xs + e) = *(const uint4*)pkv;
    }
    ps[ch][pix] = ss;
  }
  for (int i = t; i < 640; i += 256) mbL[i] = mod_b[i];
  __syncthreads();
  if (t < 128) rn[t] = 1.f / fmaxf(sqrtf(ps[0][t] + ps[1][t]), 1e-12f);
  __syncthreads();

  const int w = t >> 6, l = t & 63;
  const int g = l >> 4, cl = l & 15;
  const int pxw = w << 5;          // wave pixel base
  const int swz = (cl & 7) << 4;

  float rncol[2] = { rn[pxw + cl], rn[pxw + 16 + cl] };

  f32x4 acc2[2][4];
  #pragma unroll
  for (int pt = 0; pt < 2; ++pt)
    #pragma unroll
    for (int nt = 0; nt < 4; ++nt) acc2[pt][nt] = (f32x4){0.f, 0.f, 0.f, 0.f};

  for (int i = 0; i < 10; ++i) {
    const int n0 = i << 6;
    bf16x8 bf2[2][4];
    #pragma unroll
    for (int kt = 0; kt < 2; ++kt)
      #pragma unroll
      for (int nt = 0; nt < 4; ++nt)
        bf2[kt][nt] = *(const bf16x8*)&c1wF[(size_t)((nt << 4) + cl) * 640 + n0 + kt * 32 + g * 8];

    f32x4 acc1[4][2];
    #pragma unroll
    for (int ct = 0; ct < 4; ++ct)
      #pragma unroll
      for (int pt = 0; pt < 2; ++pt) acc1[ct][pt] = (f32x4){0.f, 0.f, 0.f, 0.f};
    #pragma unroll
    for (int ks = 0; ks < 4; ++ks) {
      bf16x8 xf[2];
      #pragma unroll
      for (int pt = 0; pt < 2; ++pt) {
        int pix = pxw + (pt << 4) + cl;
        int e = (pix * 256 + ks * 64 + g * 16) ^ swz;
        xf[pt] = *(const bf16x8*)((const char*)xs + e);
      }
      #pragma unroll
      for (int ct = 0; ct < 4; ++ct) {
        bf16x8 wf = *(const bf16x8*)&wG1[(size_t)(n0 + (ct << 4) + cl) * 128 + ks * 32 + g * 8];
        acc1[ct][0] = __builtin_amdgcn_mfma_f32_16x16x32_bf16(wf, xf[0], acc1[ct][0], 0, 0, 0);
        acc1[ct][1] = __builtin_amdgcn_mfma_f32_16x16x32_bf16(wf, xf[1], acc1[ct][1], 0, 0, 0);
      }
    }

    char* mbuf = (char*)modL[i & 1];
    #pragma unroll
    for (int pt = 0; pt < 2; ++pt) {
      int pix = pxw + (pt << 4) + cl;
      float rv = rncol[pt];
      #pragma unroll
      for (int ct = 0; ct < 4; ++ct) {
        float4 mb4 = *(const float4*)&mbL[n0 + (ct << 4) + (g << 2)];
        f32x4 a = acc1[ct][pt];
        float m[4];
        #pragma unroll
        for (int r = 0; r < 4; ++r) {
          float z = a[r] * rv + ((const float*)&mb4)[r];
          m[r] = __builtin_amdgcn_rcpf(1.f + __expf(-z));
        }
        u32 lo, hi;
        asm("v_cvt_pk_bf16_f32 %0, %1, %2" : "=v"(lo) : "v"(m[0]), "v"(m[1]));
        asm("v_cvt_pk_bf16_f32 %0, %1, %2" : "=v"(hi) : "v"(m[2]), "v"(m[3]));
        int e = (pix * 128 + ct * 32 + g * 8) ^ swz;
        uint2 st = { lo, hi };
        *(uint2*)(mbuf + e) = st;
      }
    }
    __syncthreads();

    #pragma unroll
    for (int kt = 0; kt < 2; ++kt) {
      bf16x8 af[2];
      #pragma unroll
      for (int pt = 0; pt < 2; ++pt) {
        int pix = pxw + (pt << 4) + cl;
        int e = (pix * 128 + kt * 64 + g * 16) ^ swz;
        af[pt] = *(const bf16x8*)((const char*)mbuf + e);
      }
      #pragma unroll
      for (int nt = 0; nt < 4; ++nt) {
        acc2[0][nt] = __builtin_amdgcn_mfma_f32_16x16x32_bf16(af[0], bf2[kt][nt], acc2[0][nt], 0, 0, 0);
        acc2[1][nt] = __builtin_amdgcn_mfma_f32_16x16x32_bf16(af[1], bf2[kt][nt], acc2[1][nt], 0, 0, 0);
      }
    }
  }

  // GEMM3: Sc = (x @ c2F^T) * rn
  f32x4 acc3[2][4];
  #pragma unroll
  for (int pt = 0; pt < 2; ++pt)
    #pragma unroll
    for (int nt = 0; nt < 4; ++nt) acc3[pt][nt] = (f32x4){0.f, 0.f, 0.f, 0.f};
  #pragma unroll
  for (int ks = 0; ks < 4; ++ks) {
    bf16x8 af[2];
    #pragma unroll
    for (int pt = 0; pt < 2; ++pt) {
      int pix = pxw + (pt << 4) + cl;
      int e = (pix * 256 + ks * 64 + g * 16) ^ swz;
      af[pt] = *(const bf16x8*)((const char*)xs + e);
    }
    #pragma unroll
    for (int nt = 0; nt < 4; ++nt) {
      bf16x8 bfr = *(const bf16x8*)&c2F[(size_t)((nt << 4) + cl) * 128 + ks * 32 + g * 8];
      acc3[0][nt] = __builtin_amdgcn_mfma_f32_16x16x32_bf16(af[0], bfr, acc3[0][nt], 0, 0, 0);
      acc3[1][nt] = __builtin_amdgcn_mfma_f32_16x16x32_bf16(af[1], bfr, acc3[1][nt], 0, 0, 0);
    }
  }

  // epilogue -> Snp[patch][k], k = chan*16 + p*4 + q (bf16)
  const int pgrp = (b << 5) + (y >> 2);     // b*32 + ph
  u16* Srow = Snp + ((size_t)pgrp << 16);   // *32 patches *2048
  const int p4 = (y & 3) << 2;
  #pragma unroll
  for (int pt = 0; pt < 2; ++pt) {
    int pixr = pxw + (pt << 4) + (g << 2);
    float4 rn4 = *(const float4*)&rn[pixr];
    int pw = pixr >> 2;
    #pragma unroll
    for (int nt = 0; nt < 4; ++nt) {
      int o = (nt << 4) + cl;
      float b1 = conv1_b[o];
      f32x4 a2 = acc2[pt][nt];
      uint2 s0 = { pk2(a2[0] + b1, a2[1] + b1), pk2(a2[2] + b1, a2[3] + b1) };
      *(uint2*)&Srow[((size_t)pw << 11) + (o << 4) + p4] = s0;
      float b2 = conv2_b[o];
      f32x4 a3 = acc3[pt][nt];
      uint2 s1v = { pk2(a3[0] * rn4.x + b2, a3[1] * rn4.y + b2),
                    pk2(a3[2] * rn4.z + b2, a3[3] * rn4.w + b2) };
      *(uint2*)&Srow[((size_t)pw << 11) + ((o + 64) << 4) + p4] = s1v;
    }
  }
}

// ---------------- kernel B: PatchEmbed MFMA GEMM + fused LN -> f [4096][128] -
// Block = 16 patches x 128 outputs, K=2048 in 4 chunks of 512. 256 threads.
__global__ __launch_bounds__(256) void k_pembed(
    const u16* __restrict__ Snp, const u16* __restrict__ pewB,
    const float* __restrict__ pe_b, const float* __restrict__ pe_g,
    const float* __restrict__ pe_beta, float* __restrict__ f)
{
  __shared__ u16 As[8192];        // 16 patches x 512 k, XOR-swizzled (16KB)
  __shared__ float fln[16][132];
  const int t = threadIdx.x, bx = blockIdx.x;
  const int w = t >> 6, l = t & 63;
  const int g = l >> 4, cl = l & 15;
  const size_t gbase = (size_t)bx << 15;   // bx*16 patches *2048

  f32x4 acc[2];
  acc[0] = (f32x4){0.f, 0.f, 0.f, 0.f};
  acc[1] = (f32x4){0.f, 0.f, 0.f, 0.f};

  for (int chunk = 0; chunk < 4; ++chunk) {
    __syncthreads();
    #pragma unroll
    for (int it = 0; it < 4; ++it) {
      int e8 = ((it << 8) + t) << 3;       // element index
      int pl = e8 >> 9, kk = e8 & 511;
      uint4 v = *(const uint4*)&Snp[gbase + ((size_t)pl << 11) + (chunk << 9) + kk];
      int e = (((pl << 9) + kk) << 1) ^ ((pl & 7) << 4);
      *(uint4*)((char*)As + e) = v;
    }
    __syncthreads();
    for (int ks = 0; ks < 16; ++ks) {
      int kk = (ks << 5) + (g << 3);
      int e = (((cl << 9) + kk) << 1) ^ ((cl & 7) << 4);
      bf16x8 A = *(const bf16x8*)((const char*)As + e);
      int gks = (chunk << 4) + ks;
      #pragma unroll
      for (int n2 = 0; n2 < 2; ++n2) {
        int n = (w << 1) + n2;
        bf16x8 B = *(const bf16x8*)&pewB[(size_t)((((gks << 3) + n) << 6) + l) << 3];
        acc[n2] = __builtin_amdgcn_mfma_f32_16x16x32_bf16(A, B, acc[n2], 0, 0, 0);
      }
    }
  }

  // bias + park in LDS
  #pragma unroll
  for (int n2 = 0; n2 < 2; ++n2) {
    int o = (((w << 1) + n2) << 4) + cl;
    float pb = pe_b[o];
    f32x4 a = acc[n2];
    #pragma unroll
    for (int r = 0; r < 4; ++r)
      fln[(g << 2) + r][o] = a[r] + pb;
  }
  __syncthreads();

  if (t < 128) {
    int patch = t >> 3, sub = t & 7;
    float4 v0 = *(const float4*)&fln[patch][(sub << 4) + 0];
    float4 v1 = *(const float4*)&fln[patch][(sub << 4) + 4];
    float4 v2 = *(const float4*)&fln[patch][(sub << 4) + 8];
    float4 v3 = *(const float4*)&fln[patch][(sub << 4) + 12];
    float s1 = v0.x + v0.y + v0.z + v0.w + v1.x + v1.y + v1.z + v1.w
             + v2.x + v2.y + v2.z + v2.w + v3.x + v3.y + v3.z + v3.w;
    float s2 = v0.x*v0.x + v0.y*v0.y + v0.z*v0.z + v0.w*v0.w
             + v1.x*v1.x + v1.y*v1.y + v1.z*v1.z + v1.w*v1.w
             + v2.x*v2.x + v2.y*v2.y + v2.z*v2.z + v2.w*v2.w
             + v3.x*v3.x + v3.y*v3.y + v3.z*v3.z + v3.w*v3.w;
    s1 += __shfl_xor(s1, 1); s2 += __shfl_xor(s2, 1);
    s1 += __shfl_xor(s1, 2); s2 += __shfl_xor(s2, 2);
    s1 += __shfl_xor(s1, 4); s2 += __shfl_xor(s2, 4);
    float m = s1 * (1.f / 128.f);
    float var = s2 * (1.f / 128.f) - m * m;
    float rs = rsqrtf(var + 1e-5f);
    int o0 = sub << 4;
    float* fp = f + ((size_t)((bx << 4) + patch) << 7) + o0;
    float4 gv, bv;
    #pragma unroll
    for (int i = 0; i < 4; ++i) {
      float4 vv = (i == 0) ? v0 : (i == 1) ? v1 : (i == 2) ? v2 : v3;
      gv = *(const float4*)&pe_g[o0 + (i << 2)];
      bv = *(const float4*)&pe_beta[o0 + (i << 2)];
      float4 ov = { (vv.x - m) * rs * gv.x + bv.x,
                    (vv.y - m) * rs * gv.y + bv.y,
                    (vv.z - m) * rs * gv.z + bv.z,
                    (vv.w - m) * rs * gv.w + bv.w };
      *(float4*)(fp + (i << 2)) = ov;
    }
  }
}

// ---------------- kernel C: PatchExpand + LN(32) + up-proj -> M1 NHWC -------
__global__ __launch_bounds__(128) void k_expand(
    const float* __restrict__ f, const float* __restrict__ exp_w,
    const float* __restrict__ fin_g, const float* __restrict__ fin_b,
    const float* __restrict__ up_w, const float* __restrict__ up_b,
    float* __restrict__ M1)
{
  __shared__ float fr[4][128];
  __shared__ float fe[4][512];
  __shared__ float sm[64], sr[64];
  const int t = threadIdx.x, bx = blockIdx.x;
  const int b = bx >> 8, rem = bx & 255;
  const int ph = rem >> 3, pw0 = (rem & 7) << 2;
  const int pbase = (b * 32 + ph) * 32 + pw0;

  #pragma unroll
  for (int j = 0; j < 4; ++j) fr[j][t] = f[(size_t)(pbase + j) * 128 + t];
  __syncthreads();

  float acc[4][4];
  #pragma unroll
  for (int i = 0; i < 4; ++i)
    #pragma unroll
    for (int j = 0; j < 4; ++j) acc[i][j] = 0.f;
  for (int c = 0; c < 128; ++c) {
    float f0 = fr[0][c], f1 = fr[1][c], f2 = fr[2][c], f3 = fr[3][c];
    #pragma unroll
    for (int i = 0; i < 4; ++i) {
      float w = exp_w[(size_t)c * 512 + (i << 7) + t];
      acc[i][0] = fmaf(f0, w, acc[i][0]);
      acc[i][1] = fmaf(f1, w, acc[i][1]);
      acc[i][2] = fmaf(f2, w, acc[i][2]);
      acc[i][3] = fmaf(f3, w, acc[i][3]);
    }
  }
  #pragma unroll
  for (int i = 0; i < 4; ++i)
    #pragma unroll
    for (int pp = 0; pp < 4; ++pp) fe[pp][(i << 7) + t] = acc[i][pp];
  __syncthreads();

  if (t < 64) {
    int pp = t >> 4, sp = t & 15;
    float s1 = 0.f, s2 = 0.f;
    for (int i = 0; i < 32; ++i) {
      float v = fe[pp][sp * 32 + ((t + i) & 31)];
      s1 += v; s2 += v * v;
    }
    float m = s1 * (1.f / 32.f);
    float var = s2 * (1.f / 32.f) - m * m;
    sm[t] = m; sr[t] = rsqrtf(var + 1e-5f);
  }
  __syncthreads();
  #pragma unroll
  for (int r = 0; r < 16; ++r) {
    int idx = (r << 7) + t;
    int pp = idx >> 9, j = idx & 511;
    int gi = idx >> 5, cc = idx & 31;
    float v = fe[pp][j];
    fe[pp][j] = (v - sm[gi]) * sr[gi] * fin_g[cc] + fin_b[cc];
  }
  __syncthreads();

  float uw[32];
  #pragma unroll
  for (int i = 0; i < 32; i += 4) {
    float4 u4 = *(const float4*)&up_w[t * 32 + i];
    uw[i] = u4.x; uw[i + 1] = u4.y; uw[i + 2] = u4.z; uw[i + 3] = u4.w;
  }
  float ub = up_b[t];
  for (int pp = 0; pp < 4; ++pp) {
    for (int sp = 0; sp < 16; ++sp) {
      int p = sp >> 2, q = sp & 3;
      float s = ub;
      #pragma unroll
      for (int cc = 0; cc < 32; ++cc) s = fmaf(fe[pp][sp * 32 + cc], uw[cc], s);
      M1[(((size_t)(b * 128 + ph * 4 + p)) * 128 + ((pw0 + pp) * 4 + q)) * 128 + t] = s;
    }
  }
}

// ---------------- kernel D: Xn = fwt0*(query@WpreT) + fwt1*M1, NHWC bf16 ----
__global__ __launch_bounds__(256) void k_wf(
    const float* __restrict__ Q, const u16* __restrict__ wpreT,
    const float* __restrict__ M1, const float* __restrict__ w2,
    u16* __restrict__ Xn)
{
  __shared__ u16 qs[128][136];
  __shared__ u16 wl[128][136];
  const int t = threadIdx.x, bx = blockIdx.x;
  const int b = bx >> 7;
  const int hw0 = (bx & 127) << 7;
  {
    const int pix = t & 127, ch = t >> 7;
    const float* Qp = Q + ((size_t)b << 21) + (size_t)hw0 + pix;
    #pragma unroll 8
    for (int cc = 0; cc < 64; ++cc) {
      int c = (cc << 1) + ch;
      qs[c][pix] = f2b(Qp[(size_t)c << 14]);
    }
    #pragma unroll
    for (int r = 0; r < 64; ++r) {
      int idx = (r << 8) + t;
      int c = idx >> 7, o = idx & 127;
      wl[c][o] = wpreT[(c << 7) + o];
    }
  }
  __syncthreads();
  const int to = t >> 4, tp = t & 15;
  float acc[8][8];
  #pragma unroll
  for (int i = 0; i < 8; ++i)
    #pragma unroll
    for (int j = 0; j < 8; ++j) acc[i][j] = 0.f;

  #pragma unroll 2
  for (int c = 0; c < 128; ++c) {
    float wv[8], qv[8];
    uint4 wu = *(const uint4*)&wl[c][to << 3];
    up2(wu.x, wv[0], wv[1]); up2(wu.y, wv[2], wv[3]);
    up2(wu.z, wv[4], wv[5]); up2(wu.w, wv[6], wv[7]);
    uint4 qu = *(const uint4*)&qs[c][tp << 3];
    up2(qu.x, qv[0], qv[1]); up2(qu.y, qv[2], qv[3]);
    up2(qu.z, qv[4], qv[5]); up2(qu.w, qv[6], qv[7]);
    #pragma unroll
    for (int i = 0; i < 8; ++i)
      #pragma unroll
      for (int j = 0; j < 8; ++j)
        acc[i][j] = fmaf(wv[i], qv[j], acc[i][j]);
  }
  float a0 = fmaxf(w2[0], 0.f), a1 = fmaxf(w2[1], 0.f);
  float inv = 1.f / (a0 + a1 + 1e-8f);
  float f0 = a0 * inv, f1 = a1 * inv;
  const int o0 = to << 3, p0 = tp << 3;
  #pragma unroll
  for (int j = 0; j < 8; ++j) {
    const float* mp = M1 + (((size_t)(b << 14) + hw0 + p0 + j) << 7) + o0;
    float4 u = *(const float4*)mp, v = *(const float4*)(mp + 4);
    float x0 = f0 * acc[0][j] + f1 * u.x;
    float x1 = f0 * acc[1][j] + f1 * u.y;
    float x2 = f0 * acc[2][j] + f1 * u.z;
    float x3 = f0 * acc[3][j] + f1 * u.w;
    float x4 = f0 * acc[4][j] + f1 * v.x;
    float x5 = f0 * acc[5][j] + f1 * v.y;
    float x6 = f0 * acc[6][j] + f1 * v.z;
    float x7 = f0 * acc[7][j] + f1 * v.w;
    uint4 st = { pk2(x0, x1), pk2(x2, x3), pk2(x4, x5), pk2(x6, x7) };
    *(uint4*)&Xn[(((size_t)(b << 14) + hw0 + p0 + j) << 7) + o0] = st;
  }
}

// ---------------- kernel E: 3x3 conv (MFMA implicit GEMM) + BN + ReLU6 ------
__global__ __launch_bounds__(256) void k_conv3(
    const u16* __restrict__ Xn, const u16* __restrict__ wpk,
    const float* __restrict__ bnb, float* __restrict__ out)
{
  __shared__ u16 it[12800];   // 100 rows x 128 ic, XOR-swizzled
  const int t = threadIdx.x, bx = blockIdx.x;
  const int b = bx >> 8, rem = bx & 255;
  const int ty8 = (rem >> 4) << 3, tx8 = (rem & 15) << 3;
  const int y0 = ty8 - 1, x0 = tx8 - 1;

  for (int idx = t; idx < 1600; idx += 256) {
    int ri = idx >> 4, cc = idx & 15;
    int gy = y0 + ri / 10, gx = x0 + ri % 10;
    uint4 v = {0u, 0u, 0u, 0u};
    if (gy >= 0 && gy < 128 && gx >= 0 && gx < 128)
      v = *(const uint4*)&Xn[(((size_t)(b << 14) + (gy << 7) + gx) << 7) + (cc << 3)];
    int e = (ri << 7) + (cc << 3);
    e ^= (ri & 7) << 3;
    *(uint4*)&it[e] = v;
  }
  __syncthreads();

  const int w = t >> 6, l = t & 63;
  const int g = l >> 4, cl = l & 15;

  f32x4 acc[4][2];
  #pragma unroll
  for (int m = 0; m < 4; ++m)
    #pragma unroll
    for (int nn = 0; nn < 2; ++nn)
      acc[m][nn] = (f32x4){0.f, 0.f, 0.f, 0.f};

  int ri0[4];
  #pragma unroll
  for (int m = 0; m < 4; ++m) {
    int p = (m << 4) + cl;
    ri0[m] = (p >> 3) * 10 + (p & 7);
  }

  for (int ks = 0; ks < 4; ++ks) {
    #pragma unroll
    for (int tap = 0; tap < 9; ++tap) {
      const int dy = tap / 3, dx = tap % 3;
      bf16x8 A[4];
      #pragma unroll
      for (int m = 0; m < 4; ++m) {
        int ri = ri0[m] + dy * 10 + dx;
        int e = (ri << 7) + (ks << 5) + (g << 3);
        e ^= (ri & 7) << 3;
        A[m] = *(const bf16x8*)&it[e];
      }
      #pragma unroll
      for (int nn = 0; nn < 2; ++nn) {
        int n = (w << 1) + nn;
        bf16x8 B = *(const bf16x8*)&wpk[((((ks * 9 + tap) << 3) + n) << 9) + (l << 3)];
        #pragma unroll
        for (int m = 0; m < 4; ++m)
          acc[m][nn] = __builtin_amdgcn_mfma_f32_16x16x32_bf16(A[m], B, acc[m][nn], 0, 0, 0);
      }
    }
  }

  #pragma unroll
  for (int m = 0; m < 4; ++m) {
    int p = (m << 4) + (g << 2);
    int py = p >> 3, px = p & 7;
    #pragma unroll
    for (int nn = 0; nn < 2; ++nn) {
      int n = (w << 1) + nn;
      int o = (n << 4) + cl;
      float bb = bnb[o];
      f32x4 a = acc[m][nn];
      float4 v = { fminf(fmaxf(a[0] + bb, 0.f), 6.f),
                   fminf(fmaxf(a[1] + bb, 0.f), 6.f),
                   fminf(fmaxf(a[2] + bb, 0.f), 6.f),
                   fminf(fmaxf(a[3] + bb, 0.f), 6.f) };
      *(float4*)&out[((size_t)((b << 7) + o) << 14) + ((ty8 + py) << 7) + tx8 + px] = v;
    }
  }
}

extern "C" void kernel_launch(void* const* d_in, const int* in_sizes, int n_in,
                              void* d_out, int out_size, void* d_ws, size_t ws_size,
                              hipStream_t stream) {
  const float* Structure = (const float*)d_in[0];
  const float* query     = (const float*)d_in[1];
  const float* m_items   = (const float*)d_in[2];
  const float* mod_w     = (const float*)d_in[3];
  const float* mod_b     = (const float*)d_in[4];
  const float* conv1_w   = (const float*)d_in[5];
  const float* conv1_b   = (const float*)d_in[6];
  const float* conv2_w   = (const float*)d_in[7];
  const float* conv2_b   = (const float*)d_in[8];
  const float* pe_w      = (const float*)d_in[9];
  const float* pe_b      = (const float*)d_in[10];
  const float* pe_g      = (const float*)d_in[11];
  const float* pe_beta   = (const float*)d_in[12];
  const float* exp_w     = (const float*)d_in[13];
  const float* fin_g     = (const float*)d_in[14];
  const float* fin_b     = (const float*)d_in[15];
  const float* up_w      = (const float*)d_in[16];
  const float* up_b      = (const float*)d_in[17];
  const float* wf_w2     = (const float*)d_in[18];
  const float* wf_pre_w  = (const float*)d_in[19];
  const float* wf_post_w = (const float*)d_in[20];
  const float* wf_bn_g   = (const float*)d_in[21];
  const float* wf_bn_b   = (const float*)d_in[22];

  char* ws = (char*)d_ws;
  u16*   Snp = (u16*)(ws + 0);               // 16,777,216 B (bf16 im2col)
  float* f  = (float*)(ws + 33554432);       //  2,097,152 B
  float* M1 = (float*)(ws + 35651584);       // 33,554,432 B (NHWC)
  u16*   Xn = (u16*)(ws + 0);                // alias Snp (dead after k_pembed)
  u16* wG1   = (u16*)(ws + 69206016);        // 163,840 B
  u16* c1wF  = (u16*)(ws + 69369856);        //  81,920 B
  u16* c2F   = (u16*)(ws + 69451776);        //  16,384 B
  u16* wpreT = (u16*)(ws + 69468160);        //  32,768 B
  u16* wpk   = (u16*)(ws + 69500928);        // 294,912 B
  u16* pewB  = (u16*)(ws + 69795840);        // 524,288 B -> end 70,320,128 B

  k_prep<<<2176, 256, 0, stream>>>(mod_w, conv1_w, m_items, conv2_w, wf_pre_w,
                                   wf_post_w, wf_bn_g, pe_w,
                                   wG1, c1wF, c2F, wpreT, wpk, pewB);
  k_read<<<512, 256, 0, stream>>>(Structure, wG1, c1wF, c2F, mod_b,
                                  conv1_b, conv2_b, Snp);
  k_pembed<<<256, 256, 0, stream>>>(Snp, pewB, pe_b, pe_g, pe_beta, f);
  k_expand<<<1024, 128, 0, stream>>>(f, exp_w, fin_g, fin_b, up_w, up_b, M1);
  k_wf<<<512, 256, 0, stream>>>(query, wpreT, M1, wf_w2, Xn);
  k_conv3<<<1024, 256, 0, stream>>>(Xn, wpk, wf_bn_b, (float*)d_out);
}

// Round 5
// 216.107 us; speedup vs baseline: 3.6781x; 1.0520x over previous
//
#include <hip/hip_runtime.h>

typedef unsigned short u16;
typedef unsigned int u32;
typedef __attribute__((ext_vector_type(8))) short bf16x8;
typedef __attribute__((ext_vector_type(4))) float f32x4;

__device__ __forceinline__ float b2f(u16 h) {
  union { u32 u; float f; } v; v.u = ((u32)h) << 16; return v.f;
}
__device__ __forceinline__ u16 f2b(float x) {
  union { float f; u32 u; } v; v.f = x;
  u32 u = v.u;
  return (u16)((u + 0x7FFFu + ((u >> 16) & 1u)) >> 16);  // RTN-even
}
__device__ __forceinline__ void up2(u32 u, float& lo, float& hi) {
  union { u32 x; float f; } a, b;
  a.x = u << 16; b.x = u & 0xFFFF0000u;
  lo = a.f; hi = b.f;
}
__device__ __forceinline__ u32 pk2(float lo, float hi) {
  return (u32)f2b(lo) | ((u32)f2b(hi) << 16);
}

// ---------------- prep: weight transposes / folds (bf16) ----------------
// wG1  [chan=640][c=128] = mod_w
// c1wF [o=64][k=640]     = conv1_w[o][k] * m_items[k]
// c2F  [o=64][c=128]     = conv2_w
// wpreT[c][128]          = wf_pre_w[o][c]
// wpk: conv3 weights in MFMA B-fragment order
// pewB: patch-embed weights in MFMA B-fragment order over k' = p*512+c*4+q:
//   pewB[((gks*8+n)*64+lane)*8+i] = pe_w[o=n*16+(lane&15)][k(k')], k'=gks*32+(lane>>4)*8+i
__global__ __launch_bounds__(256) void k_prep(
    const float* __restrict__ mod_w, const float* __restrict__ conv1_w,
    const float* __restrict__ m_items, const float* __restrict__ conv2_w,
    const float* __restrict__ wf_pre_w, const float* __restrict__ wf_post_w,
    const float* __restrict__ wf_bn_g, const float* __restrict__ pe_w,
    u16* __restrict__ wG1, u16* __restrict__ c1wF, u16* __restrict__ c2F,
    u16* __restrict__ wpreT, u16* __restrict__ wpk, u16* __restrict__ pewB)
{
  int idx = blockIdx.x * 256 + threadIdx.x;
  if (idx < 81920) {
    wG1[idx] = f2b(mod_w[idx]);
  } else if (idx < 122880) {
    int i = idx - 81920; int k = i % 640;
    c1wF[i] = f2b(conv1_w[i] * m_items[k]);
  } else if (idx < 131072) {
    int i = idx - 122880;
    c2F[i] = f2b(conv2_w[i]);
  } else if (idx < 147456) {
    int i = idx - 131072; int c = i >> 7, o = i & 127;
    wpreT[i] = f2b(wf_pre_w[o * 128 + c]);
  } else if (idx < 294912) {
    int i2 = idx - 147456;
    int e = i2 & 7;
    int r = i2 >> 3;
    int lane = r & 63; r >>= 6;
    int n = r & 7; r >>= 3;          // r = ks*9+tap, 0..35
    int tap = r % 9, ks = r / 9;
    int o = (n << 4) + (lane & 15);
    int ic = (ks << 5) + ((lane >> 4) << 3) + e;
    int dy = tap / 3, dx = tap % 3;
    float scale = wf_bn_g[o] * rsqrtf(1.f + 1e-5f);
    wpk[i2] = f2b(wf_post_w[((o * 128 + ic) * 3 + dy) * 3 + dx] * scale);
  } else if (idx < 557056) {
    int i = idx - 294912;            // 0..262143
    int e = i & 7;
    int r = i >> 3;
    int lane = r & 63; r >>= 6;
    int n = r & 7;
    int gks = r >> 3;                // 0..63
    int o = (n << 4) + (lane & 15);
    int kp = (gks << 5) + ((lane >> 4) << 3) + e;   // k' index
    int p = kp >> 9, c = (kp >> 2) & 127, q = kp & 3;
    int k = c * 16 + p * 4 + q;                     // original pe_w k
    pewB[i] = f2b(pe_w[o * 2048 + k]);
  }
}

// ---------------- kernel A: fused read() -> Snp [4096 patches][2048] bf16 ---
// Block = one image row (128 px), 256 threads = 4 waves.
// GEMM1 (mod, K=128) swapped orient; sigmoid -> swizzled LDS; GEMM2 (K=640);
// GEMM3 (conv2). Epilogue packs into im2col layout with k' = p*512+c*4+q:
// block writes dense per-patch stripes (no partial-line HBM writes).
__global__ __launch_bounds__(256) void k_read(
    const float* __restrict__ S, const u16* __restrict__ wG1,
    const u16* __restrict__ c1wF, const u16* __restrict__ c2F,
    const float* __restrict__ mod_b,
    const float* __restrict__ conv1_b, const float* __restrict__ conv2_b,
    u16* __restrict__ Snp)
{
  __shared__ u16 xs[16384];        // [pix=128][c=128] bf16, XOR-swizzled
  __shared__ u16 modL[8192];       // [pix=128][kk=64] bf16, XOR-swizzled
  __shared__ float rn[128];
  __shared__ float ps[2][128];
  __shared__ float mbL[640];

  const int t = threadIdx.x;
  const int b = blockIdx.x >> 7;
  const int y = blockIdx.x & 127;
  const int hw0 = y << 7;

  { // stage x (unnormalized bf16) + sumsq
    const int pix = t & 127, ch = t >> 7;
    const float* Sp = S + ((size_t)b << 21) + (size_t)hw0 + pix;
    float ss = 0.f;
    #pragma unroll
    for (int c0 = 0; c0 < 64; c0 += 8) {
      float v[8]; u32 pkv[4];
      #pragma unroll
      for (int j = 0; j < 8; ++j) {
        v[j] = Sp[(size_t)(ch * 64 + c0 + j) << 14];
        ss += v[j] * v[j];
      }
      #pragma unroll
      for (int j = 0; j < 4; ++j) pkv[j] = pk2(v[2 * j], v[2 * j + 1]);
      int e = pix * 256 + (ch * 64 + c0) * 2;
      e ^= (pix & 7) << 4;
      *(uint4*)((char*)xs + e) = *(const uint4*)pkv;
    }
    ps[ch][pix] = ss;
  }
  for (int i = t; i < 640; i += 256) mbL[i] = mod_b[i];
  __syncthreads();
  if (t < 128) rn[t] = 1.f / fmaxf(sqrtf(ps[0][t] + ps[1][t]), 1e-12f);
  __syncthreads();

  const int w = t >> 6, l = t & 63;
  const int g = l >> 4, cl = l & 15;
  const int pxw = w << 5;          // wave pixel base
  const int swz = (cl & 7) << 4;

  float rncol[2] = { rn[pxw + cl], rn[pxw + 16 + cl] };

  f32x4 acc2[2][4];
  #pragma unroll
  for (int pt = 0; pt < 2; ++pt)
    #pragma unroll
    for (int nt = 0; nt < 4; ++nt) acc2[pt][nt] = (f32x4){0.f, 0.f, 0.f, 0.f};

  for (int i = 0; i < 10; ++i) {
    const int n0 = i << 6;
    bf16x8 bf2[2][4];
    #pragma unroll
    for (int kt = 0; kt < 2; ++kt)
      #pragma unroll
      for (int nt = 0; nt < 4; ++nt)
        bf2[kt][nt] = *(const bf16x8*)&c1wF[(size_t)((nt << 4) + cl) * 640 + n0 + kt * 32 + g * 8];

    f32x4 acc1[4][2];
    #pragma unroll
    for (int ct = 0; ct < 4; ++ct)
      #pragma unroll
      for (int pt = 0; pt < 2; ++pt) acc1[ct][pt] = (f32x4){0.f, 0.f, 0.f, 0.f};
    #pragma unroll
    for (int ks = 0; ks < 4; ++ks) {
      bf16x8 xf[2];
      #pragma unroll
      for (int pt = 0; pt < 2; ++pt) {
        int pix = pxw + (pt << 4) + cl;
        int e = (pix * 256 + ks * 64 + g * 16) ^ swz;
        xf[pt] = *(const bf16x8*)((const char*)xs + e);
      }
      #pragma unroll
      for (int ct = 0; ct < 4; ++ct) {
        bf16x8 wf = *(const bf16x8*)&wG1[(size_t)(n0 + (ct << 4) + cl) * 128 + ks * 32 + g * 8];
        acc1[ct][0] = __builtin_amdgcn_mfma_f32_16x16x32_bf16(wf, xf[0], acc1[ct][0], 0, 0, 0);
        acc1[ct][1] = __builtin_amdgcn_mfma_f32_16x16x32_bf16(wf, xf[1], acc1[ct][1], 0, 0, 0);
      }
    }

    __syncthreads();   // all GEMM2 readers of previous iter are done

    #pragma unroll
    for (int pt = 0; pt < 2; ++pt) {
      int pix = pxw + (pt << 4) + cl;
      float rv = rncol[pt];
      #pragma unroll
      for (int ct = 0; ct < 4; ++ct) {
        float4 mb4 = *(const float4*)&mbL[n0 + (ct << 4) + (g << 2)];
        f32x4 a = acc1[ct][pt];
        float m[4];
        #pragma unroll
        for (int r = 0; r < 4; ++r) {
          float z = a[r] * rv + ((const float*)&mb4)[r];
          m[r] = __builtin_amdgcn_rcpf(1.f + __expf(-z));
        }
        u32 lo, hi;
        asm("v_cvt_pk_bf16_f32 %0, %1, %2" : "=v"(lo) : "v"(m[0]), "v"(m[1]));
        asm("v_cvt_pk_bf16_f32 %0, %1, %2" : "=v"(hi) : "v"(m[2]), "v"(m[3]));
        int e = (pix * 128 + ct * 32 + g * 8) ^ swz;
        uint2 st = { lo, hi };
        *(uint2*)((char*)modL + e) = st;
      }
    }
    __syncthreads();

    #pragma unroll
    for (int kt = 0; kt < 2; ++kt) {
      bf16x8 af[2];
      #pragma unroll
      for (int pt = 0; pt < 2; ++pt) {
        int pix = pxw + (pt << 4) + cl;
        int e = (pix * 128 + kt * 64 + g * 16) ^ swz;
        af[pt] = *(const bf16x8*)((const char*)modL + e);
      }
      #pragma unroll
      for (int nt = 0; nt < 4; ++nt) {
        acc2[0][nt] = __builtin_amdgcn_mfma_f32_16x16x32_bf16(af[0], bf2[kt][nt], acc2[0][nt], 0, 0, 0);
        acc2[1][nt] = __builtin_amdgcn_mfma_f32_16x16x32_bf16(af[1], bf2[kt][nt], acc2[1][nt], 0, 0, 0);
      }
    }
  }

  // GEMM3: Sc = (x @ c2F^T) * rn
  f32x4 acc3[2][4];
  #pragma unroll
  for (int pt = 0; pt < 2; ++pt)
    #pragma unroll
    for (int nt = 0; nt < 4; ++nt) acc3[pt][nt] = (f32x4){0.f, 0.f, 0.f, 0.f};
  #pragma unroll
  for (int ks = 0; ks < 4; ++ks) {
    bf16x8 af[2];
    #pragma unroll
    for (int pt = 0; pt < 2; ++pt) {
      int pix = pxw + (pt << 4) + cl;
      int e = (pix * 256 + ks * 64 + g * 16) ^ swz;
      af[pt] = *(const bf16x8*)((const char*)xs + e);
    }
    #pragma unroll
    for (int nt = 0; nt < 4; ++nt) {
      bf16x8 bfr = *(const bf16x8*)&c2F[(size_t)((nt << 4) + cl) * 128 + ks * 32 + g * 8];
      acc3[0][nt] = __builtin_amdgcn_mfma_f32_16x16x32_bf16(af[0], bfr, acc3[0][nt], 0, 0, 0);
      acc3[1][nt] = __builtin_amdgcn_mfma_f32_16x16x32_bf16(af[1], bfr, acc3[1][nt], 0, 0, 0);
    }
  }

  // epilogue -> Snp[patch][k'], k' = p*512 + c*4 + q (bf16), p = y&3 fixed
  const int pgrp = (b << 5) + (y >> 2);     // b*32 + ph
  u16* Srow = Snp + ((size_t)pgrp << 16) + ((y & 3) << 9);
  #pragma unroll
  for (int pt = 0; pt < 2; ++pt) {
    int pixr = pxw + (pt << 4) + (g << 2);
    float4 rn4 = *(const float4*)&rn[pixr];
    int pw = pixr >> 2;
    #pragma unroll
    for (int nt = 0; nt < 4; ++nt) {
      int c = (nt << 4) + cl;
      float b1 = conv1_b[c];
      f32x4 a2 = acc2[pt][nt];
      uint2 s0 = { pk2(a2[0] + b1, a2[1] + b1), pk2(a2[2] + b1, a2[3] + b1) };
      *(uint2*)&Srow[((size_t)pw << 11) + (c << 2)] = s0;
      float b2 = conv2_b[c];
      f32x4 a3 = acc3[pt][nt];
      uint2 s1v = { pk2(a3[0] * rn4.x + b2, a3[1] * rn4.y + b2),
                    pk2(a3[2] * rn4.z + b2, a3[3] * rn4.w + b2) };
      *(uint2*)&Srow[((size_t)pw << 11) + ((c + 64) << 2)] = s1v;
    }
  }
}

// ---------------- kernel B: PatchEmbed MFMA GEMM + fused LN -> f [4096][128] -
// Block = 16 patches x 128 outputs, K=2048 in 4 chunks of 512. 256 threads.
__global__ __launch_bounds__(256) void k_pembed(
    const u16* __restrict__ Snp, const u16* __restrict__ pewB,
    const float* __restrict__ pe_b, const float* __restrict__ pe_g,
    const float* __restrict__ pe_beta, float* __restrict__ f)
{
  __shared__ u16 As[8192];        // 16 patches x 512 k, XOR-swizzled (16KB)
  __shared__ float fln[16][132];
  const int t = threadIdx.x, bx = blockIdx.x;
  const int w = t >> 6, l = t & 63;
  const int g = l >> 4, cl = l & 15;
  const size_t gbase = (size_t)bx << 15;   // bx*16 patches *2048

  f32x4 acc[2];
  acc[0] = (f32x4){0.f, 0.f, 0.f, 0.f};
  acc[1] = (f32x4){0.f, 0.f, 0.f, 0.f};

  for (int chunk = 0; chunk < 4; ++chunk) {
    __syncthreads();
    #pragma unroll
    for (int it = 0; it < 4; ++it) {
      int e8 = ((it << 8) + t) << 3;       // element index
      int pl = e8 >> 9, kk = e8 & 511;
      uint4 v = *(const uint4*)&Snp[gbase + ((size_t)pl << 11) + (chunk << 9) + kk];
      int e = (((pl << 9) + kk) << 1) ^ ((pl & 7) << 4);
      *(uint4*)((char*)As + e) = v;
    }
    __syncthreads();
    for (int ks = 0; ks < 16; ++ks) {
      int kk = (ks << 5) + (g << 3);
      int e = (((cl << 9) + kk) << 1) ^ ((cl & 7) << 4);
      bf16x8 A = *(const bf16x8*)((const char*)As + e);
      int gks = (chunk << 4) + ks;
      #pragma unroll
      for (int n2 = 0; n2 < 2; ++n2) {
        int n = (w << 1) + n2;
        bf16x8 B = *(const bf16x8*)&pewB[(size_t)((((gks << 3) + n) << 6) + l) << 3];
        acc[n2] = __builtin_amdgcn_mfma_f32_16x16x32_bf16(A, B, acc[n2], 0, 0, 0);
      }
    }
  }

  // bias + park in LDS
  #pragma unroll
  for (int n2 = 0; n2 < 2; ++n2) {
    int o = (((w << 1) + n2) << 4) + cl;
    float pb = pe_b[o];
    f32x4 a = acc[n2];
    #pragma unroll
    for (int r = 0; r < 4; ++r)
      fln[(g << 2) + r][o] = a[r] + pb;
  }
  __syncthreads();

  if (t < 128) {
    int patch = t >> 3, sub = t & 7;
    float4 v0 = *(const float4*)&fln[patch][(sub << 4) + 0];
    float4 v1 = *(const float4*)&fln[patch][(sub << 4) + 4];
    float4 v2 = *(const float4*)&fln[patch][(sub << 4) + 8];
    float4 v3 = *(const float4*)&fln[patch][(sub << 4) + 12];
    float s1 = v0.x + v0.y + v0.z + v0.w + v1.x + v1.y + v1.z + v1.w
             + v2.x + v2.y + v2.z + v2.w + v3.x + v3.y + v3.z + v3.w;
    float s2 = v0.x*v0.x + v0.y*v0.y + v0.z*v0.z + v0.w*v0.w
             + v1.x*v1.x + v1.y*v1.y + v1.z*v1.z + v1.w*v1.w
             + v2.x*v2.x + v2.y*v2.y + v2.z*v2.z + v2.w*v2.w
             + v3.x*v3.x + v3.y*v3.y + v3.z*v3.z + v3.w*v3.w;
    s1 += __shfl_xor(s1, 1); s2 += __shfl_xor(s2, 1);
    s1 += __shfl_xor(s1, 2); s2 += __shfl_xor(s2, 2);
    s1 += __shfl_xor(s1, 4); s2 += __shfl_xor(s2, 4);
    float m = s1 * (1.f / 128.f);
    float var = s2 * (1.f / 128.f) - m * m;
    float rs = rsqrtf(var + 1e-5f);
    int o0 = sub << 4;
    float* fp = f + ((size_t)((bx << 4) + patch) << 7) + o0;
    float4 gv, bv;
    #pragma unroll
    for (int i = 0; i < 4; ++i) {
      float4 vv = (i == 0) ? v0 : (i == 1) ? v1 : (i == 2) ? v2 : v3;
      gv = *(const float4*)&pe_g[o0 + (i << 2)];
      bv = *(const float4*)&pe_beta[o0 + (i << 2)];
      float4 ov = { (vv.x - m) * rs * gv.x + bv.x,
                    (vv.y - m) * rs * gv.y + bv.y,
                    (vv.z - m) * rs * gv.z + bv.z,
                    (vv.w - m) * rs * gv.w + bv.w };
      *(float4*)(fp + (i << 2)) = ov;
    }
  }
}

// ---------------- kernel C: PatchExpand + LN(32) + up-proj -> M1 NHWC -------
__global__ __launch_bounds__(128) void k_expand(
    const float* __restrict__ f, const float* __restrict__ exp_w,
    const float* __restrict__ fin_g, const float* __restrict__ fin_b,
    const float* __restrict__ up_w, const float* __restrict__ up_b,
    float* __restrict__ M1)
{
  __shared__ float fr[4][128];
  __shared__ float fe[4][512];
  __shared__ float sm[64], sr[64];
  const int t = threadIdx.x, bx = blockIdx.x;
  const int b = bx >> 8, rem = bx & 255;
  const int ph = rem >> 3, pw0 = (rem & 7) << 2;
  const int pbase = (b * 32 + ph) * 32 + pw0;

  #pragma unroll
  for (int j = 0; j < 4; ++j) fr[j][t] = f[(size_t)(pbase + j) * 128 + t];
  __syncthreads();

  float acc[4][4];
  #pragma unroll
  for (int i = 0; i < 4; ++i)
    #pragma unroll
    for (int j = 0; j < 4; ++j) acc[i][j] = 0.f;
  for (int c = 0; c < 128; ++c) {
    float f0 = fr[0][c], f1 = fr[1][c], f2 = fr[2][c], f3 = fr[3][c];
    #pragma unroll
    for (int i = 0; i < 4; ++i) {
      float w = exp_w[(size_t)c * 512 + (i << 7) + t];
      acc[i][0] = fmaf(f0, w, acc[i][0]);
      acc[i][1] = fmaf(f1, w, acc[i][1]);
      acc[i][2] = fmaf(f2, w, acc[i][2]);
      acc[i][3] = fmaf(f3, w, acc[i][3]);
    }
  }
  #pragma unroll
  for (int i = 0; i < 4; ++i)
    #pragma unroll
    for (int pp = 0; pp < 4; ++pp) fe[pp][(i << 7) + t] = acc[i][pp];
  __syncthreads();

  if (t < 64) {
    int pp = t >> 4, sp = t & 15;
    float s1 = 0.f, s2 = 0.f;
    for (int i = 0; i < 32; ++i) {
      float v = fe[pp][sp * 32 + ((t + i) & 31)];
      s1 += v; s2 += v * v;
    }
    float m = s1 * (1.f / 32.f);
    float var = s2 * (1.f / 32.f) - m * m;
    sm[t] = m; sr[t] = rsqrtf(var + 1e-5f);
  }
  __syncthreads();
  #pragma unroll
  for (int r = 0; r < 16; ++r) {
    int idx = (r << 7) + t;
    int pp = idx >> 9, j = idx & 511;
    int gi = idx >> 5, cc = idx & 31;
    float v = fe[pp][j];
    fe[pp][j] = (v - sm[gi]) * sr[gi] * fin_g[cc] + fin_b[cc];
  }
  __syncthreads();

  float uw[32];
  #pragma unroll
  for (int i = 0; i < 32; i += 4) {
    float4 u4 = *(const float4*)&up_w[t * 32 + i];
    uw[i] = u4.x; uw[i + 1] = u4.y; uw[i + 2] = u4.z; uw[i + 3] = u4.w;
  }
  float ub = up_b[t];
  for (int pp = 0; pp < 4; ++pp) {
    for (int sp = 0; sp < 16; ++sp) {
      int p = sp >> 2, q = sp & 3;
      float s = ub;
      #pragma unroll
      for (int cc = 0; cc < 32; ++cc) s = fmaf(fe[pp][sp * 32 + cc], uw[cc], s);
      M1[(((size_t)(b * 128 + ph * 4 + p)) * 128 + ((pw0 + pp) * 4 + q)) * 128 + t] = s;
    }
  }
}

// ---------------- kernel D: Xn = fwt0*(query@WpreT) + fwt1*M1, NHWC bf16 ----
__global__ __launch_bounds__(256) void k_wf(
    const float* __restrict__ Q, const u16* __restrict__ wpreT,
    const float* __restrict__ M1, const float* __restrict__ w2,
    u16* __restrict__ Xn)
{
  __shared__ u16 qs[128][136];
  __shared__ u16 wl[128][136];
  const int t = threadIdx.x, bx = blockIdx.x;
  const int b = bx >> 7;
  const int hw0 = (bx & 127) << 7;
  {
    const int pix = t & 127, ch = t >> 7;
    const float* Qp = Q + ((size_t)b << 21) + (size_t)hw0 + pix;
    #pragma unroll 8
    for (int cc = 0; cc < 64; ++cc) {
      int c = (cc << 1) + ch;
      qs[c][pix] = f2b(Qp[(size_t)c << 14]);
    }
    #pragma unroll
    for (int r = 0; r < 64; ++r) {
      int idx = (r << 8) + t;
      int c = idx >> 7, o = idx & 127;
      wl[c][o] = wpreT[(c << 7) + o];
    }
  }
  __syncthreads();
  const int to = t >> 4, tp = t & 15;
  float acc[8][8];
  #pragma unroll
  for (int i = 0; i < 8; ++i)
    #pragma unroll
    for (int j = 0; j < 8; ++j) acc[i][j] = 0.f;

  #pragma unroll 2
  for (int c = 0; c < 128; ++c) {
    float wv[8], qv[8];
    uint4 wu = *(const uint4*)&wl[c][to << 3];
    up2(wu.x, wv[0], wv[1]); up2(wu.y, wv[2], wv[3]);
    up2(wu.z, wv[4], wv[5]); up2(wu.w, wv[6], wv[7]);
    uint4 qu = *(const uint4*)&qs[c][tp << 3];
    up2(qu.x, qv[0], qv[1]); up2(qu.y, qv[2], qv[3]);
    up2(qu.z, qv[4], qv[5]); up2(qu.w, qv[6], qv[7]);
    #pragma unroll
    for (int i = 0; i < 8; ++i)
      #pragma unroll
      for (int j = 0; j < 8; ++j)
        acc[i][j] = fmaf(wv[i], qv[j], acc[i][j]);
  }
  float a0 = fmaxf(w2[0], 0.f), a1 = fmaxf(w2[1], 0.f);
  float inv = 1.f / (a0 + a1 + 1e-8f);
  float f0 = a0 * inv, f1 = a1 * inv;
  const int o0 = to << 3, p0 = tp << 3;
  #pragma unroll
  for (int j = 0; j < 8; ++j) {
    const float* mp = M1 + (((size_t)(b << 14) + hw0 + p0 + j) << 7) + o0;
    float4 u = *(const float4*)mp, v = *(const float4*)(mp + 4);
    float x0 = f0 * acc[0][j] + f1 * u.x;
    float x1 = f0 * acc[1][j] + f1 * u.y;
    float x2 = f0 * acc[2][j] + f1 * u.z;
    float x3 = f0 * acc[3][j] + f1 * u.w;
    float x4 = f0 * acc[4][j] + f1 * v.x;
    float x5 = f0 * acc[5][j] + f1 * v.y;
    float x6 = f0 * acc[6][j] + f1 * v.z;
    float x7 = f0 * acc[7][j] + f1 * v.w;
    uint4 st = { pk2(x0, x1), pk2(x2, x3), pk2(x4, x5), pk2(x6, x7) };
    *(uint4*)&Xn[(((size_t)(b << 14) + hw0 + p0 + j) << 7) + o0] = st;
  }
}

// ---------------- kernel E: 3x3 conv (MFMA implicit GEMM) + BN + ReLU6 ------
__global__ __launch_bounds__(256) void k_conv3(
    const u16* __restrict__ Xn, const u16* __restrict__ wpk,
    const float* __restrict__ bnb, float* __restrict__ out)
{
  __shared__ u16 it[12800];   // 100 rows x 128 ic, XOR-swizzled
  const int t = threadIdx.x, bx = blockIdx.x;
  const int b = bx >> 8, rem = bx & 255;
  const int ty8 = (rem >> 4) << 3, tx8 = (rem & 15) << 3;
  const int y0 = ty8 - 1, x0 = tx8 - 1;

  for (int idx = t; idx < 1600; idx += 256) {
    int ri = idx >> 4, cc = idx & 15;
    int gy = y0 + ri / 10, gx = x0 + ri % 10;
    uint4 v = {0u, 0u, 0u, 0u};
    if (gy >= 0 && gy < 128 && gx >= 0 && gx < 128)
      v = *(const uint4*)&Xn[(((size_t)(b << 14) + (gy << 7) + gx) << 7) + (cc << 3)];
    int e = (ri << 7) + (cc << 3);
    e ^= (ri & 7) << 3;
    *(uint4*)&it[e] = v;
  }
  __syncthreads();

  const int w = t >> 6, l = t & 63;
  const int g = l >> 4, cl = l & 15;

  f32x4 acc[4][2];
  #pragma unroll
  for (int m = 0; m < 4; ++m)
    #pragma unroll
    for (int nn = 0; nn < 2; ++nn)
      acc[m][nn] = (f32x4){0.f, 0.f, 0.f, 0.f};

  int ri0[4];
  #pragma unroll
  for (int m = 0; m < 4; ++m) {
    int p = (m << 4) + cl;
    ri0[m] = (p >> 3) * 10 + (p & 7);
  }

  for (int ks = 0; ks < 4; ++ks) {
    #pragma unroll
    for (int tap = 0; tap < 9; ++tap) {
      const int dy = tap / 3, dx = tap % 3;
      bf16x8 A[4];
      #pragma unroll
      for (int m = 0; m < 4; ++m) {
        int ri = ri0[m] + dy * 10 + dx;
        int e = (ri << 7) + (ks << 5) + (g << 3);
        e ^= (ri & 7) << 3;
        A[m] = *(const bf16x8*)&it[e];
      }
      #pragma unroll
      for (int nn = 0; nn < 2; ++nn) {
        int n = (w << 1) + nn;
        bf16x8 B = *(const bf16x8*)&wpk[((((ks * 9 + tap) << 3) + n) << 9) + (l << 3)];
        #pragma unroll
        for (int m = 0; m < 4; ++m)
          acc[m][nn] = __builtin_amdgcn_mfma_f32_16x16x32_bf16(A[m], B, acc[m][nn], 0, 0, 0);
      }
    }
  }

  #pragma unroll
  for (int m = 0; m < 4; ++m) {
    int p = (m << 4) + (g << 2);
    int py = p >> 3, px = p & 7;
    #pragma unroll
    for (int nn = 0; nn < 2; ++nn) {
      int n = (w << 1) + nn;
      int o = (n << 4) + cl;
      float bb = bnb[o];
      f32x4 a = acc[m][nn];
      float4 v = { fminf(fmaxf(a[0] + bb, 0.f), 6.f),
                   fminf(fmaxf(a[1] + bb, 0.f), 6.f),
                   fminf(fmaxf(a[2] + bb, 0.f), 6.f),
                   fminf(fmaxf(a[3] + bb, 0.f), 6.f) };
      *(float4*)&out[((size_t)((b << 7) + o) << 14) + ((ty8 + py) << 7) + tx8 + px] = v;
    }
  }
}

extern "C" void kernel_launch(void* const* d_in, const int* in_sizes, int n_in,
                              void* d_out, int out_size, void* d_ws, size_t ws_size,
                              hipStream_t stream) {
  const float* Structure = (const float*)d_in[0];
  const float* query     = (const float*)d_in[1];
  const float* m_items   = (const float*)d_in[2];
  const float* mod_w     = (const float*)d_in[3];
  const float* mod_b     = (const float*)d_in[4];
  const float* conv1_w   = (const float*)d_in[5];
  const float* conv1_b   = (const float*)d_in[6];
  const float* conv2_w   = (const float*)d_in[7];
  const float* conv2_b   = (const float*)d_in[8];
  const float* pe_w      = (const float*)d_in[9];
  const float* pe_b      = (const float*)d_in[10];
  const float* pe_g      = (const float*)d_in[11];
  const float* pe_beta   = (const float*)d_in[12];
  const float* exp_w     = (const float*)d_in[13];
  const float* fin_g     = (const float*)d_in[14];
  const float* fin_b     = (const float*)d_in[15];
  const float* up_w      = (const float*)d_in[16];
  const float* up_b      = (const float*)d_in[17];
  const float* wf_w2     = (const float*)d_in[18];
  const float* wf_pre_w  = (const float*)d_in[19];
  const float* wf_post_w = (const float*)d_in[20];
  const float* wf_bn_g   = (const float*)d_in[21];
  const float* wf_bn_b   = (const float*)d_in[22];

  char* ws = (char*)d_ws;
  u16*   Snp = (u16*)(ws + 0);               // 16,777,216 B (bf16 im2col, k'-order)
  float* f  = (float*)(ws + 33554432);       //  2,097,152 B
  float* M1 = (float*)(ws + 35651584);       // 33,554,432 B (NHWC)
  u16*   Xn = (u16*)(ws + 0);                // alias Snp (dead after k_pembed)
  u16* wG1   = (u16*)(ws + 69206016);        // 163,840 B
  u16* c1wF  = (u16*)(ws + 69369856);        //  81,920 B
  u16* c2F   = (u16*)(ws + 69451776);        //  16,384 B
  u16* wpreT = (u16*)(ws + 69468160);        //  32,768 B
  u16* wpk   = (u16*)(ws + 69500928);        // 294,912 B
  u16* pewB  = (u16*)(ws + 69795840);        // 524,288 B -> end 70,320,128 B

  k_prep<<<2176, 256, 0, stream>>>(mod_w, conv1_w, m_items, conv2_w, wf_pre_w,
                                   wf_post_w, wf_bn_g, pe_w,
                                   wG1, c1wF, c2F, wpreT, wpk, pewB);
  k_read<<<512, 256, 0, stream>>>(Structure, wG1, c1wF, c2F, mod_b,
                                  conv1_b, conv2_b, Snp);
  k_pembed<<<256, 256, 0, stream>>>(Snp, pewB, pe_b, pe_g, pe_beta, f);
  k_expand<<<1024, 128, 0, stream>>>(f, exp_w, fin_g, fin_b, up_w, up_b, M1);
  k_wf<<<512, 256, 0, stream>>>(query, wpreT, M1, wf_w2, Xn);
  k_conv3<<<1024, 256, 0, stream>>>(Xn, wpk, wf_bn_b, (float*)d_out);
}